// Round 10
// baseline (984.571 us; speedup 1.0000x reference)
//
#include <hip/hip_runtime.h>
#include <hip/hip_bf16.h>

typedef __hip_bfloat16 bf16;

#define B_ 2
#define T_ 1024
#define C_ 1024
#define H_ 16
#define N_ 64

using short8 = __attribute__((ext_vector_type(8))) short;
using f32x4 = __attribute__((ext_vector_type(4))) float;

__device__ __forceinline__ float us2f(unsigned short u) {
  return __uint_as_float(((unsigned int)u) << 16);
}
__device__ __forceinline__ float bs2f(short s) {
  return __uint_as_float(((unsigned int)(unsigned short)s) << 16);
}
__device__ __forceinline__ bf16 f2bf(float f) { return __float2bfloat16(f); }
__device__ __forceinline__ float sigmoidf_(float x) { return 1.0f / (1.0f + expf(-x)); }
__device__ __forceinline__ float softplusf_(float x) {
  return fmaxf(x, 0.0f) + log1pf(expf(-fabsf(x)));
}

// ---------------- K0: fused weight fp32->bf16 conversion (big weights) ------
__global__ __launch_bounds__(256) void cvt_weights_kernel(
    const float* __restrict__ s0, const float* __restrict__ s1,
    const float* __restrict__ s2, const float* __restrict__ s3,
    const float* __restrict__ s4, const float* __restrict__ s5,
    const float* __restrict__ s6,
    bf16* __restrict__ d0, bf16* __restrict__ d1, bf16* __restrict__ d2,
    bf16* __restrict__ d3, bf16* __restrict__ d4, bf16* __restrict__ d5,
    bf16* __restrict__ d6) {
  long i4 = (long)blockIdx.x * 256 + threadIdx.x;
  const float* s; bf16* d; long off;
  if (i4 < 32768) { s = s0; d = d0; off = i4; }
  else if (i4 < 294912) { s = s1; d = d1; off = i4 - 32768; }
  else if (i4 < 327680) { s = s2; d = d2; off = i4 - 294912; }
  else if (i4 < 360448) { s = s3; d = d3; off = i4 - 327680; }
  else if (i4 < 622592) { s = s4; d = d4; off = i4 - 360448; }
  else if (i4 < 884736) { s = s5; d = d5; off = i4 - 622592; }
  else { s = s6; d = d6; off = i4 - 884736; }
  float4 v = *(const float4*)(s + off * 4);
  d[off * 4 + 0] = f2bf(v.x);
  d[off * 4 + 1] = f2bf(v.y);
  d[off * 4 + 2] = f2bf(v.z);
  d[off * 4 + 3] = f2bf(v.w);
}

// ---------------- K0b: pack small LoRA-1 weights to bf16 --------------------
__global__ __launch_bounds__(256) void cvt_small_kernel(
    const float* __restrict__ tkw1, const float* __restrict__ mkw1,
    const float* __restrict__ tdw1, const float* __restrict__ taw1,
    const float* __restrict__ maw1,
    bf16* __restrict__ wsk, bf16* __restrict__ wswa) {
  long i4 = (long)blockIdx.x * 256 + threadIdx.x;  // < 32768
  const float* s; bf16* d; long so, dof;
  if (i4 < 4096) { s = tkw1; so = i4; d = wsk; dof = i4; }
  else if (i4 < 8192) { s = mkw1; so = i4 - 4096; d = wsk; dof = i4; }
  else if (i4 < 24576) { s = tdw1; so = i4 - 8192; d = wswa; dof = i4 - 8192; }
  else if (i4 < 28672) { s = taw1; so = i4 - 24576; d = wswa; dof = i4 - 8192; }
  else { s = maw1; so = i4 - 28672; d = wswa; dof = i4 - 8192; }
  float4 v = *(const float4*)(s + so * 4);
  d[dof * 4 + 0] = f2bf(v.x);
  d[dof * 4 + 1] = f2bf(v.y);
  d[dof * 4 + 2] = f2bf(v.z);
  d[dof * 4 + 3] = f2bf(v.w);
}

// ---------------- K0c: LoRA-2 weights to bf16 -------------------------------
__global__ __launch_bounds__(256) void cvt_small2_kernel(
    const float* __restrict__ tmw2, const float* __restrict__ tdw2,
    const float* __restrict__ tkw2, const float* __restrict__ taw2,
    const float* __restrict__ maw2, const float* __restrict__ mkw2,
    bf16* __restrict__ tmw2b, bf16* __restrict__ tdw2b,
    bf16* __restrict__ tkw2b, bf16* __restrict__ taw2b,
    bf16* __restrict__ maw2b, bf16* __restrict__ mkw2b) {
  long i4 = (long)blockIdx.x * 256 + threadIdx.x;  // < 65536
  const float* s; bf16* d; long off;
  if (i4 < 32768) { s = tmw2; d = tmw2b; off = i4; }
  else if (i4 < 49152) { s = tdw2; d = tdw2b; off = i4 - 32768; }
  else if (i4 < 53248) { s = tkw2; d = tkw2b; off = i4 - 49152; }
  else if (i4 < 57344) { s = taw2; d = taw2b; off = i4 - 53248; }
  else if (i4 < 61440) { s = maw2; d = maw2b; off = i4 - 57344; }
  else { s = mkw2; d = mkw2b; off = i4 - 61440; }
  float4 v = *(const float4*)(s + off * 4);
  d[off * 4 + 0] = f2bf(v.x);
  d[off * 4 + 1] = f2bf(v.y);
  d[off * 4 + 2] = f2bf(v.z);
  d[off * 4 + 3] = f2bf(v.w);
}

// ---------------- K1: token shift (writes xx f32, xxx bf16) -----------------
__global__ __launch_bounds__(256) void shift_kernel(
    const float* __restrict__ x, const float* __restrict__ tmx,
    float* __restrict__ xx, bf16* __restrict__ xxxb) {
  long idx = (long)blockIdx.x * 256 + threadIdx.x;  // < B*T*C
  int c = (int)(idx & (C_ - 1));
  int t = (int)((idx >> 10) & (T_ - 1));
  float xv = x[idx];
  float xp = (t > 0) ? x[idx - C_] : 0.0f;
  float d = xp - xv;
  xx[idx] = d;
  xxxb[idx] = f2bf(xv + d * tmx[c]);
}

// ---------------- MFMA GEMM: C = A(bf16 MxK) * W^T (W bf16 NxK) -------------
__global__ __launch_bounds__(256) void gemm_mfma_kernel(
    const bf16* __restrict__ A, const bf16* __restrict__ W,
    float* __restrict__ Cf, bf16* __restrict__ Cb,
    int M, int N, int K, int actN) {
  __shared__ __align__(16) bf16 As[64][72];  // 144B row stride, 16B aligned
  __shared__ __align__(16) bf16 Ws[64][72];
  int tid = threadIdx.x;
  int m0 = blockIdx.y << 6, n0 = blockIdx.x << 6;
  int srow = tid >> 2, skg = (tid & 3) << 4;   // staging: row, 16 bf16 per thread
  int wv = tid >> 6, lane = tid & 63;
  int fr = lane & 15, fq = lane >> 4;
  f32x4 acc0 = {0.f, 0.f, 0.f, 0.f}, acc1 = acc0, acc2 = acc0, acc3 = acc0;
  bool wok = (n0 + srow) < N;
  const bf16* Ap = A + (long)(m0 + srow) * K + skg;
  const bf16* Wp = W + (long)(n0 + srow) * K + skg;
  short8 zz = {0, 0, 0, 0, 0, 0, 0, 0};
  for (int k0 = 0; k0 < K; k0 += 64) {
    *(short8*)&As[srow][skg] = *(const short8*)(Ap + k0);
    *(short8*)&As[srow][skg + 8] = *(const short8*)(Ap + k0 + 8);
    *(short8*)&Ws[srow][skg] = wok ? *(const short8*)(Wp + k0) : zz;
    *(short8*)&Ws[srow][skg + 8] = wok ? *(const short8*)(Wp + k0 + 8) : zz;
    __syncthreads();
#pragma unroll
    for (int kk = 0; kk < 2; kk++) {
      int ko = (fq << 3) + (kk << 5);
      short8 af = *(const short8*)&As[(wv << 4) + fr][ko];
      short8 b0 = *(const short8*)&Ws[fr][ko];
      short8 b1 = *(const short8*)&Ws[16 + fr][ko];
      short8 b2 = *(const short8*)&Ws[32 + fr][ko];
      short8 b3 = *(const short8*)&Ws[48 + fr][ko];
      acc0 = __builtin_amdgcn_mfma_f32_16x16x32_bf16(af, b0, acc0, 0, 0, 0);
      acc1 = __builtin_amdgcn_mfma_f32_16x16x32_bf16(af, b1, acc1, 0, 0, 0);
      acc2 = __builtin_amdgcn_mfma_f32_16x16x32_bf16(af, b2, acc2, 0, 0, 0);
      acc3 = __builtin_amdgcn_mfma_f32_16x16x32_bf16(af, b3, acc3, 0, 0, 0);
    }
    __syncthreads();
  }
  int orow = m0 + (wv << 4) + (fq << 2);
  int ocol = n0 + fr;
  f32x4 av[4] = {acc0, acc1, acc2, acc3};
#pragma unroll
  for (int nt = 0; nt < 4; nt++) {
    int col = ocol + (nt << 4);
    if (col < N) {
#pragma unroll
      for (int r = 0; r < 4; r++) {
        float vvv = av[nt][r];
        if (col < actN) vvv = tanhf(vvv);
        long oi = (long)(orow + r) * N + col;
        if (Cb) Cb[oi] = f2bf(vvv); else Cf[oi] = vvv;
      }
    }
  }
}

// ---------------- K3: deltas + build xrg/xwa/xk/xv (bf16 out) ---------------
__global__ __launch_bounds__(256) void mix4_kernel(
    const float* __restrict__ x, const float* __restrict__ xx,
    const float* __restrict__ mix, const float* __restrict__ tmaa,
    const bf16* __restrict__ w2b,
    bf16* __restrict__ xrg, bf16* __restrict__ xwa,
    bf16* __restrict__ xk, bf16* __restrict__ xv) {
  int m = blockIdx.x;
  int tid = threadIdx.x;
  __shared__ float mrow[128];
  if (tid < 128) mrow[tid] = mix[(long)m * 128 + tid];
  __syncthreads();
#pragma unroll
  for (int cc = 0; cc < 4; cc++) {
    int c = tid + (cc << 8);
    long off = (long)m * C_ + c;
    float xb = x[off];
    float xxv = xx[off];
    float res[4];
#pragma unroll
    for (int f = 0; f < 4; f++) {
      const short8* wp = (const short8*)(w2b + (((long)f * C_ + c) << 5));
      float dl = 0.f;
#pragma unroll
      for (int d8 = 0; d8 < 4; d8++) {
        short8 u = wp[d8];
        int db = (f << 5) + (d8 << 3);
#pragma unroll
        for (int e = 0; e < 8; e++) dl += mrow[db + e] * bs2f(u[e]);
      }
      res[f] = xb + xxv * (tmaa[f * C_ + c] + dl);
    }
    xrg[off] = f2bf(res[0]); xwa[off] = f2bf(res[1]);
    xk[off] = f2bf(res[2]); xv[off] = f2bf(res[3]);
  }
}

// ---------------- K5: stage-2 small GEMMs + gates + per-head kk norm --------
__global__ __launch_bounds__(256) void fuse2_kernel(
    const float* __restrict__ kraw, const float* __restrict__ out1,
    const float* __restrict__ out2,
    const bf16* __restrict__ dw2, const bf16* __restrict__ kkw2,
    const bf16* __restrict__ aw2, const bf16* __restrict__ maw2,
    const bf16* __restrict__ mkw2,
    const float* __restrict__ tdec, const float* __restrict__ taa,
    const float* __restrict__ tma, const float* __restrict__ tmk,
    float* __restrict__ ew, float* __restrict__ kfin,
    float* __restrict__ kkn, float* __restrict__ bbo) {
  int m = blockIdx.x, tid = threadIdx.x;
  __shared__ float w1r[64], kk1r[16], a1r[16], ma1r[16], mk1r[16];
  if (tid < 64) w1r[tid] = out2[(long)m * 96 + tid];
  else if (tid < 80) kk1r[tid - 64] = out1[(long)m * 32 + (tid - 64)];
  else if (tid < 96) a1r[tid - 80] = out2[(long)m * 96 + 64 + (tid - 80)];
  else if (tid < 112) ma1r[tid - 96] = out2[(long)m * 96 + 80 + (tid - 96)];
  else if (tid < 128) mk1r[tid - 112] = out1[(long)m * 32 + 16 + (tid - 112)];
  __syncthreads();
  float kkp[4], av[4], wv[4], kr[4], mkv[4];
  float sumsq = 0.f;
#pragma unroll
  for (int j = 0; j < 4; j++) {
    int c = (tid << 2) + j;
    long off = (long)m * C_ + c;
    float wd = 0.f;
    const short8* dp = (const short8*)(dw2 + ((long)c << 6));
#pragma unroll
    for (int d8 = 0; d8 < 8; d8++) {
      short8 u = dp[d8];
      int db = d8 << 3;
#pragma unroll
      for (int e = 0; e < 8; e++) wd += w1r[db + e] * bs2f(u[e]);
    }
    float w = -softplusf_(-(tdec[c] + wd)) - 0.5f;
    wv[j] = w;
    float kd = 0.f, ad = 0.f, mad = 0.f, mkd = 0.f;
    const short8* kp = (const short8*)(kkw2 + ((long)c << 4));
    const short8* ap = (const short8*)(aw2 + ((long)c << 4));
    const short8* mp = (const short8*)(maw2 + ((long)c << 4));
    const short8* qp = (const short8*)(mkw2 + ((long)c << 4));
#pragma unroll
    for (int d8 = 0; d8 < 2; d8++) {
      short8 u1 = kp[d8], u2 = ap[d8], u3 = mp[d8], u4 = qp[d8];
      int db = d8 << 3;
#pragma unroll
      for (int e = 0; e < 8; e++) {
        kd += kk1r[db + e] * bs2f(u1[e]);
        ad += a1r[db + e] * bs2f(u2[e]);
        mad += ma1r[db + e] * bs2f(u3[e]);
        mkd += mk1r[db + e] * bs2f(u4[e]);
      }
    }
    float krw = kraw[off];
    float kkpre = krw + kd;
    kkp[j] = kkpre;
    sumsq += kkpre * kkpre;
    float a = sigmoidf_(taa[c] + ad);
    av[j] = a;
    float ma = sigmoidf_(tma[c] + mad);
    float mk = sigmoidf_(tmk[c] + mkd);
    mkv[j] = mk;
    kr[j] = krw * (ma + a * (1.f - ma));
  }
  sumsq += __shfl_xor(sumsq, 1);
  sumsq += __shfl_xor(sumsq, 2);
  sumsq += __shfl_xor(sumsq, 4);
  sumsq += __shfl_xor(sumsq, 8);
  float rn = 1.0f / fmaxf(sqrtf(sumsq), 1e-12f);
#pragma unroll
  for (int j = 0; j < 4; j++) {
    int c = (tid << 2) + j;
    long off = (long)m * C_ + c;
    float kknv = kkp[j] * rn;
    kkn[off] = kknv;
    bbo[off] = -kknv * av[j];
    ew[off] = expf(wv[j]);
    kfin[off] = kr[j] * expf(wv[j] * mkv[j]);
  }
}

// ---------------- K6: RWKV-7 scan, cooperative block per (b,h) --------------
// 32 blocks x 256 threads. Wave w = rowgroup w (rows w*16..w*16+15) of the
// block's (b,h). Staging: each thread loads 6 float4 (one per stream) per
// 16-token chunk -> 1536 parallel loads, reg->LDS with 2 barriers (the
// GEMM-ladder pattern the compiler reliably pipelines). Loads for chunk c+1
// issue before computing chunk c. lane=(r<<2)|q: row=w*16+r, lane holds 16
// consecutive keys [q*16,q*16+16). shfl_xor 1,2 = DPP quad_perm.
#define SCHUNK 16
__global__ __launch_bounds__(256) void scan_kernel(
    const float* __restrict__ rB, const float* __restrict__ ewB,
    const float* __restrict__ kB, const float* __restrict__ vB,
    const float* __restrict__ kkB, const float* __restrict__ bbB,
    float* __restrict__ yB) {
  __shared__ __align__(16) float lds[6][SCHUNK * 64];
  int bh = blockIdx.x;           // 0..31
  int b = bh >> 4, h = bh & 15;
  int tid = threadIdx.x;
  int wave = tid >> 6, lane = tid & 63;
  int r = lane >> 2, q = lane & 3;
  int row = (wave << 4) + r;
  int kq = q << 4;
  const long base = ((long)b * T_) * C_ + (h << 6);
  const float* s0 = kkB + base;
  const float* s1 = ewB + base;
  const float* s2 = kB + base;
  const float* s3 = bbB + base;
  const float* s4 = rB + base;
  const float* s5 = vB + base;
  int stok = tid >> 4;           // staging token within chunk (0..15)
  int spc = (tid & 15) << 2;     // float offset within token row
  int lo = (stok << 6) + spc;    // LDS float offset
  float4 rb0, rb1, rb2, rb3, rb4, rb5;
  auto loadc = [&](int c) {
    long go = (long)((c << 4) + stok) * C_ + spc;
    rb0 = *(const float4*)(s0 + go);
    rb1 = *(const float4*)(s1 + go);
    rb2 = *(const float4*)(s2 + go);
    rb3 = *(const float4*)(s3 + go);
    rb4 = *(const float4*)(s4 + go);
    rb5 = *(const float4*)(s5 + go);
  };
  float S[16];
#pragma unroll
  for (int j = 0; j < 16; j++) S[j] = 0.f;
  loadc(0);
  for (int c = 0; c < T_ / SCHUNK; c++) {
    __syncthreads();
    *(float4*)&lds[0][lo] = rb0;
    *(float4*)&lds[1][lo] = rb1;
    *(float4*)&lds[2][lo] = rb2;
    *(float4*)&lds[3][lo] = rb3;
    *(float4*)&lds[4][lo] = rb4;
    *(float4*)&lds[5][lo] = rb5;
    __syncthreads();
    if (c + 1 < T_ / SCHUNK) loadc(c + 1);
#pragma unroll 4
    for (int tt = 0; tt < SCHUNK; tt++) {
      int tb = (tt << 6) + kq;
      float4 kk0 = *(const float4*)&lds[0][tb];
      float4 kk1 = *(const float4*)&lds[0][tb + 4];
      float4 kk2 = *(const float4*)&lds[0][tb + 8];
      float4 kk3 = *(const float4*)&lds[0][tb + 12];
      float cv = lds[5][(tt << 6) + row];
      float p0 = S[0] * kk0.x + S[1] * kk0.y + S[2] * kk0.z + S[3] * kk0.w;
      float p1 = S[4] * kk1.x + S[5] * kk1.y + S[6] * kk1.z + S[7] * kk1.w;
      float p2 = S[8] * kk2.x + S[9] * kk2.y + S[10] * kk2.z + S[11] * kk2.w;
      float p3 = S[12] * kk3.x + S[13] * kk3.y + S[14] * kk3.z + S[15] * kk3.w;
      float sab = (p0 + p1) + (p2 + p3);
      sab += __shfl_xor(sab, 1);
      sab += __shfl_xor(sab, 2);
      float4 ew0 = *(const float4*)&lds[1][tb];
      float4 ew1 = *(const float4*)&lds[1][tb + 4];
      float4 ew2 = *(const float4*)&lds[1][tb + 8];
      float4 ew3 = *(const float4*)&lds[1][tb + 12];
      float4 bb0 = *(const float4*)&lds[3][tb];
      float4 bb1 = *(const float4*)&lds[3][tb + 4];
      float4 bb2 = *(const float4*)&lds[3][tb + 8];
      float4 bb3 = *(const float4*)&lds[3][tb + 12];
      float4 k0 = *(const float4*)&lds[2][tb];
      float4 k1 = *(const float4*)&lds[2][tb + 4];
      float4 k2 = *(const float4*)&lds[2][tb + 8];
      float4 k3 = *(const float4*)&lds[2][tb + 12];
      S[0] = S[0] * ew0.x + sab * bb0.x + cv * k0.x;
      S[1] = S[1] * ew0.y + sab * bb0.y + cv * k0.y;
      S[2] = S[2] * ew0.z + sab * bb0.z + cv * k0.z;
      S[3] = S[3] * ew0.w + sab * bb0.w + cv * k0.w;
      S[4] = S[4] * ew1.x + sab * bb1.x + cv * k1.x;
      S[5] = S[5] * ew1.y + sab * bb1.y + cv * k1.y;
      S[6] = S[6] * ew1.z + sab * bb1.z + cv * k1.z;
      S[7] = S[7] * ew1.w + sab * bb1.w + cv * k1.w;
      S[8] = S[8] * ew2.x + sab * bb2.x + cv * k2.x;
      S[9] = S[9] * ew2.y + sab * bb2.y + cv * k2.y;
      S[10] = S[10] * ew2.z + sab * bb2.z + cv * k2.z;
      S[11] = S[11] * ew2.w + sab * bb2.w + cv * k2.w;
      S[12] = S[12] * ew3.x + sab * bb3.x + cv * k3.x;
      S[13] = S[13] * ew3.y + sab * bb3.y + cv * k3.y;
      S[14] = S[14] * ew3.z + sab * bb3.z + cv * k3.z;
      S[15] = S[15] * ew3.w + sab * bb3.w + cv * k3.w;
      float4 r0 = *(const float4*)&lds[4][tb];
      float4 r1 = *(const float4*)&lds[4][tb + 4];
      float4 r2 = *(const float4*)&lds[4][tb + 8];
      float4 r3 = *(const float4*)&lds[4][tb + 12];
      float y0 = S[0] * r0.x + S[1] * r0.y + S[2] * r0.z + S[3] * r0.w;
      float y1 = S[4] * r1.x + S[5] * r1.y + S[6] * r1.z + S[7] * r1.w;
      float y2 = S[8] * r2.x + S[9] * r2.y + S[10] * r2.z + S[11] * r2.w;
      float y3 = S[12] * r3.x + S[13] * r3.y + S[14] * r3.z + S[15] * r3.w;
      float y = (y0 + y1) + (y2 + y3);
      y += __shfl_xor(y, 1);
      y += __shfl_xor(y, 2);
      if (q == 0) yB[base + (long)((c << 4) + tt) * C_ + row] = y;
    }
  }
}

// ---------------- K7: GroupNorm + bonus + gate (bf16 out) -------------------
__global__ __launch_bounds__(256) void gnout_kernel(
    const float* __restrict__ y, const float* __restrict__ r,
    const float* __restrict__ kf, const float* __restrict__ v,
    const float* __restrict__ g,
    const float* __restrict__ lnw, const float* __restrict__ lnb,
    const float* __restrict__ fa, bf16* __restrict__ z) {
  int tid = threadIdx.x;
  int w = tid >> 6, lane = tid & 63;
  int gi = (blockIdx.x << 2) + w;  // (b*T+t)*H + h
  int h = gi & 15, mt = gi >> 4;
  long off = (long)mt * C_ + (h << 6) + lane;
  float yv = y[off];
  float s = yv;
  s += __shfl_xor(s, 1); s += __shfl_xor(s, 2); s += __shfl_xor(s, 4);
  s += __shfl_xor(s, 8); s += __shfl_xor(s, 16); s += __shfl_xor(s, 32);
  float mu = s * (1.0f / 64.0f);
  float d = yv - mu;
  float s2 = d * d;
  s2 += __shfl_xor(s2, 1); s2 += __shfl_xor(s2, 2); s2 += __shfl_xor(s2, 4);
  s2 += __shfl_xor(s2, 8); s2 += __shfl_xor(s2, 16); s2 += __shfl_xor(s2, 32);
  float var = s2 * (1.0f / 64.0f);
  int hc = (h << 6) + lane;
  float dot = r[off] * kf[off] * fa[hc];
  dot += __shfl_xor(dot, 1); dot += __shfl_xor(dot, 2); dot += __shfl_xor(dot, 4);
  dot += __shfl_xor(dot, 8); dot += __shfl_xor(dot, 16); dot += __shfl_xor(dot, 32);
  float yn = d * rsqrtf(var + 0.00064f) * lnw[hc] + lnb[hc];
  z[off] = f2bf((yn + dot * v[off]) * g[off]);
}

extern "C" void kernel_launch(void* const* d_in, const int* in_sizes, int n_in,
                              void* d_out, int out_size, void* d_ws, size_t ws_size,
                              hipStream_t stream) {
  const float* x = (const float*)d_in[0];
  const float* tmx = (const float*)d_in[1];
  const float* tmaa = (const float*)d_in[2];
  const float* tmw1 = (const float*)d_in[3];
  const float* tmw2 = (const float*)d_in[4];
  const float* tdec = (const float*)d_in[5];
  const float* tdw1 = (const float*)d_in[6];
  const float* tdw2 = (const float*)d_in[7];
  const float* taa5 = (const float*)d_in[8];
  const float* taw1 = (const float*)d_in[9];
  const float* taw2 = (const float*)d_in[10];
  const float* tkw1 = (const float*)d_in[11];
  const float* tkw2 = (const float*)d_in[12];
  const float* gw1 = (const float*)d_in[13];
  const float* gw2 = (const float*)d_in[14];
  const float* tmia = (const float*)d_in[15];
  const float* maw1 = (const float*)d_in[16];
  const float* maw2 = (const float*)d_in[17];
  const float* tmik = (const float*)d_in[18];
  const float* mkw1 = (const float*)d_in[19];
  const float* mkw2 = (const float*)d_in[20];
  const float* wrec = (const float*)d_in[21];
  const float* wkey = (const float*)d_in[22];
  const float* wval = (const float*)d_in[23];
  const float* wout = (const float*)d_in[24];
  const float* lnw = (const float*)d_in[25];
  const float* lnb = (const float*)d_in[26];
  const float* faaa = (const float*)d_in[27];

  const long MT = 2048, CC = 1024;
  char* base = (char*)d_ws;
  float* xx = (float*)base;    base += MT * CC * 4;   // also y
  bf16* xxxb = (bf16*)base;    base += MT * CC * 2;
  bf16* xrgb = (bf16*)base;    base += MT * CC * 2;   // ┐ kfin overlays (8MB)
  bf16* xwab = (bf16*)base;    base += MT * CC * 2;   // ┘
  bf16* xkb = (bf16*)base;     base += MT * CC * 2;   // ┐ kkn overlays (8MB)
  bf16* xvb = (bf16*)base;     base += MT * CC * 2;   // ┘
  float* rr = (float*)base;    base += MT * CC * 4;
  float* kraw = (float*)base;  base += MT * CC * 4;   // also ew
  float* vv = (float*)base;    base += MT * CC * 4;
  float* gg = (float*)base;    base += MT * CC * 4;
  float* bbo = (float*)base;   base += MT * CC * 4;
  float* mix = (float*)base;   base += MT * 128 * 4;
  bf16* g1b = (bf16*)base;     base += MT * 128 * 2;
  float* out1 = (float*)base;  base += MT * 32 * 4;   // [kk1|mk1]
  float* out2 = (float*)base;  base += MT * 96 * 4;   // [w1|a1|ma1]
  bf16* zb = (bf16*)base;      base += MT * CC * 2;
  bf16* tmw1b = (bf16*)base;   base += 128 * CC * 2;
  bf16* wrecb = (bf16*)base;   base += CC * CC * 2;
  bf16* gw1b = (bf16*)base;    base += 128 * CC * 2;
  bf16* gw2b = (bf16*)base;    base += CC * 128 * 2;
  bf16* wkeyb = (bf16*)base;   base += CC * CC * 2;
  bf16* wvalb = (bf16*)base;   base += CC * CC * 2;
  bf16* woutb = (bf16*)base;   base += CC * CC * 2;
  bf16* wskb = (bf16*)base;    base += 32 * CC * 2;
  bf16* wswab = (bf16*)base;   base += 96 * CC * 2;
  bf16* tmw2b = (bf16*)base;   base += 4 * CC * 32 * 2;
  bf16* tdw2b = (bf16*)base;   base += CC * 64 * 2;
  bf16* tkw2b = (bf16*)base;   base += CC * 16 * 2;
  bf16* taw2b = (bf16*)base;   base += CC * 16 * 2;
  bf16* maw2b = (bf16*)base;   base += CC * 16 * 2;
  bf16* mkw2b = (bf16*)base;   base += CC * 16 * 2;
  // aliases (dead-buffer reuse, verified non-overlapping in time):
  float* ew = kraw;            // fuse2 reads kraw then writes ew at same offs
  float* kfin = (float*)xrgb;  // xrg/xwa bf16 dead before fuse2
  float* kkn = (float*)xkb;    // xk/xv bf16 dead before fuse2
  float* y = xx;               // xx dead after mix4

  auto gemm_m = [&](const bf16* A, const bf16* W, float* Cf, bf16* Cb,
                    int M, int N, int K, int actN) {
    dim3 grid((N + 63) / 64, M / 64);
    gemm_mfma_kernel<<<grid, 256, 0, stream>>>(A, W, Cf, Cb, M, N, K, actN);
  };

  cvt_weights_kernel<<<4480, 256, 0, stream>>>(
      tmw1, wrec, gw1, gw2, wkey, wval, wout,
      tmw1b, wrecb, gw1b, gw2b, wkeyb, wvalb, woutb);
  cvt_small_kernel<<<128, 256, 0, stream>>>(tkw1, mkw1, tdw1, taw1, maw1,
                                            wskb, wswab);
  cvt_small2_kernel<<<256, 256, 0, stream>>>(tmw2, tdw2, tkw2, taw2, maw2, mkw2,
                                             tmw2b, tdw2b, tkw2b, taw2b,
                                             maw2b, mkw2b);
  shift_kernel<<<8192, 256, 0, stream>>>(x, tmx, xx, xxxb);
  gemm_m(xxxb, tmw1b, mix, nullptr, 2048, 128, 1024, 128);   // tanh all
  mix4_kernel<<<2048, 256, 0, stream>>>(x, xx, mix, tmaa, tmw2b,
                                        xrgb, xwab, xkb, xvb);
  gemm_m(xrgb, wrecb, rr, nullptr, 2048, 1024, 1024, 0);
  gemm_m(xrgb, gw1b, nullptr, g1b, 2048, 128, 1024, 128);    // tanh all
  gemm_m(g1b, gw2b, gg, nullptr, 2048, 1024, 128, 0);
  gemm_m(xkb, wkeyb, kraw, nullptr, 2048, 1024, 1024, 0);
  gemm_m(xkb, wskb, out1, nullptr, 2048, 32, 1024, 16);      // tanh cols<16
  gemm_m(xvb, wvalb, vv, nullptr, 2048, 1024, 1024, 0);
  gemm_m(xwab, wswab, out2, nullptr, 2048, 96, 1024, 64);    // tanh cols<64
  fuse2_kernel<<<2048, 256, 0, stream>>>(kraw, out1, out2,
                                         tdw2b, tkw2b, taw2b, maw2b, mkw2b,
                                         tdec, taa5, tmia, tmik,
                                         ew, kfin, kkn, bbo);
  scan_kernel<<<32, 256, 0, stream>>>(rr, ew, kfin, vv, kkn, bbo, y);
  gnout_kernel<<<8192, 256, 0, stream>>>(y, rr, kfin, vv, gg, lnw, lnb, faaa, zb);
  gemm_m(zb, woutb, (float*)d_out, nullptr, 2048, 1024, 1024, 0);
}

// Round 11
// 872.639 us; speedup vs baseline: 1.1283x; 1.1283x over previous
//
#include <hip/hip_runtime.h>
#include <hip/hip_bf16.h>

typedef __hip_bfloat16 bf16;

#define B_ 2
#define T_ 1024
#define C_ 1024
#define H_ 16
#define N_ 64

using short8 = __attribute__((ext_vector_type(8))) short;
using f32x4 = __attribute__((ext_vector_type(4))) float;

__device__ __forceinline__ float us2f(unsigned short u) {
  return __uint_as_float(((unsigned int)u) << 16);
}
__device__ __forceinline__ float bs2f(short s) {
  return __uint_as_float(((unsigned int)(unsigned short)s) << 16);
}
__device__ __forceinline__ bf16 f2bf(float f) { return __float2bfloat16(f); }
__device__ __forceinline__ float sigmoidf_(float x) { return 1.0f / (1.0f + expf(-x)); }
__device__ __forceinline__ float softplusf_(float x) {
  return fmaxf(x, 0.0f) + log1pf(expf(-fabsf(x)));
}
// quad-lane butterfly adds via DPP quad_perm (pure VALU; ~4-8 cyc, no LDS
// crossbar — HIP __shfl_xor lowers to ds_bpermute even for masks 1/2).
__device__ __forceinline__ float qadd12(float x) {
  int a = __builtin_amdgcn_update_dpp(0, __float_as_int(x), 0xB1, 0xF, 0xF, true);
  x += __int_as_float(a);                       // xor 1: quad_perm [1,0,3,2]
  int b = __builtin_amdgcn_update_dpp(0, __float_as_int(x), 0x4E, 0xF, 0xF, true);
  return x + __int_as_float(b);                 // xor 2: quad_perm [2,3,0,1]
}

// ---------------- K0: fused weight fp32->bf16 conversion (big weights) ------
__global__ __launch_bounds__(256) void cvt_weights_kernel(
    const float* __restrict__ s0, const float* __restrict__ s1,
    const float* __restrict__ s2, const float* __restrict__ s3,
    const float* __restrict__ s4, const float* __restrict__ s5,
    const float* __restrict__ s6,
    bf16* __restrict__ d0, bf16* __restrict__ d1, bf16* __restrict__ d2,
    bf16* __restrict__ d3, bf16* __restrict__ d4, bf16* __restrict__ d5,
    bf16* __restrict__ d6) {
  long i4 = (long)blockIdx.x * 256 + threadIdx.x;
  const float* s; bf16* d; long off;
  if (i4 < 32768) { s = s0; d = d0; off = i4; }
  else if (i4 < 294912) { s = s1; d = d1; off = i4 - 32768; }
  else if (i4 < 327680) { s = s2; d = d2; off = i4 - 294912; }
  else if (i4 < 360448) { s = s3; d = d3; off = i4 - 327680; }
  else if (i4 < 622592) { s = s4; d = d4; off = i4 - 360448; }
  else if (i4 < 884736) { s = s5; d = d5; off = i4 - 622592; }
  else { s = s6; d = d6; off = i4 - 884736; }
  float4 v = *(const float4*)(s + off * 4);
  d[off * 4 + 0] = f2bf(v.x);
  d[off * 4 + 1] = f2bf(v.y);
  d[off * 4 + 2] = f2bf(v.z);
  d[off * 4 + 3] = f2bf(v.w);
}

// ---------------- K0b: pack small LoRA-1 weights to bf16 --------------------
__global__ __launch_bounds__(256) void cvt_small_kernel(
    const float* __restrict__ tkw1, const float* __restrict__ mkw1,
    const float* __restrict__ tdw1, const float* __restrict__ taw1,
    const float* __restrict__ maw1,
    bf16* __restrict__ wsk, bf16* __restrict__ wswa) {
  long i4 = (long)blockIdx.x * 256 + threadIdx.x;  // < 32768
  const float* s; bf16* d; long so, dof;
  if (i4 < 4096) { s = tkw1; so = i4; d = wsk; dof = i4; }
  else if (i4 < 8192) { s = mkw1; so = i4 - 4096; d = wsk; dof = i4; }
  else if (i4 < 24576) { s = tdw1; so = i4 - 8192; d = wswa; dof = i4 - 8192; }
  else if (i4 < 28672) { s = taw1; so = i4 - 24576; d = wswa; dof = i4 - 8192; }
  else { s = maw1; so = i4 - 28672; d = wswa; dof = i4 - 8192; }
  float4 v = *(const float4*)(s + so * 4);
  d[dof * 4 + 0] = f2bf(v.x);
  d[dof * 4 + 1] = f2bf(v.y);
  d[dof * 4 + 2] = f2bf(v.z);
  d[dof * 4 + 3] = f2bf(v.w);
}

// ---------------- K0c: LoRA-2 weights to bf16 -------------------------------
__global__ __launch_bounds__(256) void cvt_small2_kernel(
    const float* __restrict__ tmw2, const float* __restrict__ tdw2,
    const float* __restrict__ tkw2, const float* __restrict__ taw2,
    const float* __restrict__ maw2, const float* __restrict__ mkw2,
    bf16* __restrict__ tmw2b, bf16* __restrict__ tdw2b,
    bf16* __restrict__ tkw2b, bf16* __restrict__ taw2b,
    bf16* __restrict__ maw2b, bf16* __restrict__ mkw2b) {
  long i4 = (long)blockIdx.x * 256 + threadIdx.x;  // < 65536
  const float* s; bf16* d; long off;
  if (i4 < 32768) { s = tmw2; d = tmw2b; off = i4; }
  else if (i4 < 49152) { s = tdw2; d = tdw2b; off = i4 - 32768; }
  else if (i4 < 53248) { s = tkw2; d = tkw2b; off = i4 - 49152; }
  else if (i4 < 57344) { s = taw2; d = taw2b; off = i4 - 53248; }
  else if (i4 < 61440) { s = maw2; d = maw2b; off = i4 - 57344; }
  else { s = mkw2; d = mkw2b; off = i4 - 61440; }
  float4 v = *(const float4*)(s + off * 4);
  d[off * 4 + 0] = f2bf(v.x);
  d[off * 4 + 1] = f2bf(v.y);
  d[off * 4 + 2] = f2bf(v.z);
  d[off * 4 + 3] = f2bf(v.w);
}

// ---------------- K1: token shift (writes xx f32, xxx bf16) -----------------
__global__ __launch_bounds__(256) void shift_kernel(
    const float* __restrict__ x, const float* __restrict__ tmx,
    float* __restrict__ xx, bf16* __restrict__ xxxb) {
  long idx = (long)blockIdx.x * 256 + threadIdx.x;  // < B*T*C
  int c = (int)(idx & (C_ - 1));
  int t = (int)((idx >> 10) & (T_ - 1));
  float xv = x[idx];
  float xp = (t > 0) ? x[idx - C_] : 0.0f;
  float d = xp - xv;
  xx[idx] = d;
  xxxb[idx] = f2bf(xv + d * tmx[c]);
}

// ---------------- MFMA GEMM: C = A(bf16 MxK) * W^T (W bf16 NxK) -------------
__global__ __launch_bounds__(256) void gemm_mfma_kernel(
    const bf16* __restrict__ A, const bf16* __restrict__ W,
    float* __restrict__ Cf, bf16* __restrict__ Cb,
    int M, int N, int K, int actN) {
  __shared__ __align__(16) bf16 As[64][72];  // 144B row stride, 16B aligned
  __shared__ __align__(16) bf16 Ws[64][72];
  int tid = threadIdx.x;
  int m0 = blockIdx.y << 6, n0 = blockIdx.x << 6;
  int srow = tid >> 2, skg = (tid & 3) << 4;   // staging: row, 16 bf16 per thread
  int wv = tid >> 6, lane = tid & 63;
  int fr = lane & 15, fq = lane >> 4;
  f32x4 acc0 = {0.f, 0.f, 0.f, 0.f}, acc1 = acc0, acc2 = acc0, acc3 = acc0;
  bool wok = (n0 + srow) < N;
  const bf16* Ap = A + (long)(m0 + srow) * K + skg;
  const bf16* Wp = W + (long)(n0 + srow) * K + skg;
  short8 zz = {0, 0, 0, 0, 0, 0, 0, 0};
  for (int k0 = 0; k0 < K; k0 += 64) {
    *(short8*)&As[srow][skg] = *(const short8*)(Ap + k0);
    *(short8*)&As[srow][skg + 8] = *(const short8*)(Ap + k0 + 8);
    *(short8*)&Ws[srow][skg] = wok ? *(const short8*)(Wp + k0) : zz;
    *(short8*)&Ws[srow][skg + 8] = wok ? *(const short8*)(Wp + k0 + 8) : zz;
    __syncthreads();
#pragma unroll
    for (int kk = 0; kk < 2; kk++) {
      int ko = (fq << 3) + (kk << 5);
      short8 af = *(const short8*)&As[(wv << 4) + fr][ko];
      short8 b0 = *(const short8*)&Ws[fr][ko];
      short8 b1 = *(const short8*)&Ws[16 + fr][ko];
      short8 b2 = *(const short8*)&Ws[32 + fr][ko];
      short8 b3 = *(const short8*)&Ws[48 + fr][ko];
      acc0 = __builtin_amdgcn_mfma_f32_16x16x32_bf16(af, b0, acc0, 0, 0, 0);
      acc1 = __builtin_amdgcn_mfma_f32_16x16x32_bf16(af, b1, acc1, 0, 0, 0);
      acc2 = __builtin_amdgcn_mfma_f32_16x16x32_bf16(af, b2, acc2, 0, 0, 0);
      acc3 = __builtin_amdgcn_mfma_f32_16x16x32_bf16(af, b3, acc3, 0, 0, 0);
    }
    __syncthreads();
  }
  int orow = m0 + (wv << 4) + (fq << 2);
  int ocol = n0 + fr;
  f32x4 av[4] = {acc0, acc1, acc2, acc3};
#pragma unroll
  for (int nt = 0; nt < 4; nt++) {
    int col = ocol + (nt << 4);
    if (col < N) {
#pragma unroll
      for (int r = 0; r < 4; r++) {
        float vvv = av[nt][r];
        if (col < actN) vvv = tanhf(vvv);
        long oi = (long)(orow + r) * N + col;
        if (Cb) Cb[oi] = f2bf(vvv); else Cf[oi] = vvv;
      }
    }
  }
}

// ---------------- K3: deltas + build xrg/xwa/xk/xv (bf16 out) ---------------
__global__ __launch_bounds__(256) void mix4_kernel(
    const float* __restrict__ x, const float* __restrict__ xx,
    const float* __restrict__ mix, const float* __restrict__ tmaa,
    const bf16* __restrict__ w2b,
    bf16* __restrict__ xrg, bf16* __restrict__ xwa,
    bf16* __restrict__ xk, bf16* __restrict__ xv) {
  int m = blockIdx.x;
  int tid = threadIdx.x;
  __shared__ float mrow[128];
  if (tid < 128) mrow[tid] = mix[(long)m * 128 + tid];
  __syncthreads();
#pragma unroll
  for (int cc = 0; cc < 4; cc++) {
    int c = tid + (cc << 8);
    long off = (long)m * C_ + c;
    float xb = x[off];
    float xxv = xx[off];
    float res[4];
#pragma unroll
    for (int f = 0; f < 4; f++) {
      const short8* wp = (const short8*)(w2b + (((long)f * C_ + c) << 5));
      float dl = 0.f;
#pragma unroll
      for (int d8 = 0; d8 < 4; d8++) {
        short8 u = wp[d8];
        int db = (f << 5) + (d8 << 3);
#pragma unroll
        for (int e = 0; e < 8; e++) dl += mrow[db + e] * bs2f(u[e]);
      }
      res[f] = xb + xxv * (tmaa[f * C_ + c] + dl);
    }
    xrg[off] = f2bf(res[0]); xwa[off] = f2bf(res[1]);
    xk[off] = f2bf(res[2]); xv[off] = f2bf(res[3]);
  }
}

// ---------------- K5: stage-2 small GEMMs + gates + per-head kk norm --------
__global__ __launch_bounds__(256) void fuse2_kernel(
    const float* __restrict__ kraw, const float* __restrict__ out1,
    const float* __restrict__ out2,
    const bf16* __restrict__ dw2, const bf16* __restrict__ kkw2,
    const bf16* __restrict__ aw2, const bf16* __restrict__ maw2,
    const bf16* __restrict__ mkw2,
    const float* __restrict__ tdec, const float* __restrict__ taa,
    const float* __restrict__ tma, const float* __restrict__ tmk,
    float* __restrict__ ew, float* __restrict__ kfin,
    float* __restrict__ kkn, float* __restrict__ bbo) {
  int m = blockIdx.x, tid = threadIdx.x;
  __shared__ float w1r[64], kk1r[16], a1r[16], ma1r[16], mk1r[16];
  if (tid < 64) w1r[tid] = out2[(long)m * 96 + tid];
  else if (tid < 80) kk1r[tid - 64] = out1[(long)m * 32 + (tid - 64)];
  else if (tid < 96) a1r[tid - 80] = out2[(long)m * 96 + 64 + (tid - 80)];
  else if (tid < 112) ma1r[tid - 96] = out2[(long)m * 96 + 80 + (tid - 96)];
  else if (tid < 128) mk1r[tid - 112] = out1[(long)m * 32 + 16 + (tid - 112)];
  __syncthreads();
  float kkp[4], av[4], wv[4], kr[4], mkv[4];
  float sumsq = 0.f;
#pragma unroll
  for (int j = 0; j < 4; j++) {
    int c = (tid << 2) + j;
    long off = (long)m * C_ + c;
    float wd = 0.f;
    const short8* dp = (const short8*)(dw2 + ((long)c << 6));
#pragma unroll
    for (int d8 = 0; d8 < 8; d8++) {
      short8 u = dp[d8];
      int db = d8 << 3;
#pragma unroll
      for (int e = 0; e < 8; e++) wd += w1r[db + e] * bs2f(u[e]);
    }
    float w = -softplusf_(-(tdec[c] + wd)) - 0.5f;
    wv[j] = w;
    float kd = 0.f, ad = 0.f, mad = 0.f, mkd = 0.f;
    const short8* kp = (const short8*)(kkw2 + ((long)c << 4));
    const short8* ap = (const short8*)(aw2 + ((long)c << 4));
    const short8* mp = (const short8*)(maw2 + ((long)c << 4));
    const short8* qp = (const short8*)(mkw2 + ((long)c << 4));
#pragma unroll
    for (int d8 = 0; d8 < 2; d8++) {
      short8 u1 = kp[d8], u2 = ap[d8], u3 = mp[d8], u4 = qp[d8];
      int db = d8 << 3;
#pragma unroll
      for (int e = 0; e < 8; e++) {
        kd += kk1r[db + e] * bs2f(u1[e]);
        ad += a1r[db + e] * bs2f(u2[e]);
        mad += ma1r[db + e] * bs2f(u3[e]);
        mkd += mk1r[db + e] * bs2f(u4[e]);
      }
    }
    float krw = kraw[off];
    float kkpre = krw + kd;
    kkp[j] = kkpre;
    sumsq += kkpre * kkpre;
    float a = sigmoidf_(taa[c] + ad);
    av[j] = a;
    float ma = sigmoidf_(tma[c] + mad);
    float mk = sigmoidf_(tmk[c] + mkd);
    mkv[j] = mk;
    kr[j] = krw * (ma + a * (1.f - ma));
  }
  sumsq += __shfl_xor(sumsq, 1);
  sumsq += __shfl_xor(sumsq, 2);
  sumsq += __shfl_xor(sumsq, 4);
  sumsq += __shfl_xor(sumsq, 8);
  float rn = 1.0f / fmaxf(sqrtf(sumsq), 1e-12f);
#pragma unroll
  for (int j = 0; j < 4; j++) {
    int c = (tid << 2) + j;
    long off = (long)m * C_ + c;
    float kknv = kkp[j] * rn;
    kkn[off] = kknv;
    bbo[off] = -kknv * av[j];
    ew[off] = expf(wv[j]);
    kfin[off] = kr[j] * expf(wv[j] * mkv[j]);
  }
}

// ---------------- K6: RWKV-7 scan, cooperative block per (b,h) --------------
// 32 blocks x 256 threads. Wave w = rowgroup w (rows w*16..w*16+15). LDS
// staging as round 10 (perfect dedup). Reductions now via DPP quad_perm adds
// (qadd12) instead of __shfl_xor/ds_bpermute. Token unroll 8 for ds_read
// hoisting window.
#define SCHUNK 16
__global__ __launch_bounds__(256) void scan_kernel(
    const float* __restrict__ rB, const float* __restrict__ ewB,
    const float* __restrict__ kB, const float* __restrict__ vB,
    const float* __restrict__ kkB, const float* __restrict__ bbB,
    float* __restrict__ yB) {
  __shared__ __align__(16) float lds[6][SCHUNK * 64];
  int bh = blockIdx.x;           // 0..31
  int b = bh >> 4, h = bh & 15;
  int tid = threadIdx.x;
  int wave = tid >> 6, lane = tid & 63;
  int r = lane >> 2, q = lane & 3;
  int row = (wave << 4) + r;
  int kq = q << 4;
  const long base = ((long)b * T_) * C_ + (h << 6);
  const float* s0 = kkB + base;
  const float* s1 = ewB + base;
  const float* s2 = kB + base;
  const float* s3 = bbB + base;
  const float* s4 = rB + base;
  const float* s5 = vB + base;
  int stok = tid >> 4;           // staging token within chunk (0..15)
  int spc = (tid & 15) << 2;     // float offset within token row
  int lo = (stok << 6) + spc;    // LDS float offset
  float4 rb0, rb1, rb2, rb3, rb4, rb5;
  auto loadc = [&](int c) {
    long go = (long)((c << 4) + stok) * C_ + spc;
    rb0 = *(const float4*)(s0 + go);
    rb1 = *(const float4*)(s1 + go);
    rb2 = *(const float4*)(s2 + go);
    rb3 = *(const float4*)(s3 + go);
    rb4 = *(const float4*)(s4 + go);
    rb5 = *(const float4*)(s5 + go);
  };
  float S[16];
#pragma unroll
  for (int j = 0; j < 16; j++) S[j] = 0.f;
  loadc(0);
  for (int c = 0; c < T_ / SCHUNK; c++) {
    __syncthreads();
    *(float4*)&lds[0][lo] = rb0;
    *(float4*)&lds[1][lo] = rb1;
    *(float4*)&lds[2][lo] = rb2;
    *(float4*)&lds[3][lo] = rb3;
    *(float4*)&lds[4][lo] = rb4;
    *(float4*)&lds[5][lo] = rb5;
    __syncthreads();
    if (c + 1 < T_ / SCHUNK) loadc(c + 1);
#pragma unroll 8
    for (int tt = 0; tt < SCHUNK; tt++) {
      int tb = (tt << 6) + kq;
      float4 kk0 = *(const float4*)&lds[0][tb];
      float4 kk1 = *(const float4*)&lds[0][tb + 4];
      float4 kk2 = *(const float4*)&lds[0][tb + 8];
      float4 kk3 = *(const float4*)&lds[0][tb + 12];
      float cv = lds[5][(tt << 6) + row];
      float p0 = S[0] * kk0.x + S[1] * kk0.y + S[2] * kk0.z + S[3] * kk0.w;
      float p1 = S[4] * kk1.x + S[5] * kk1.y + S[6] * kk1.z + S[7] * kk1.w;
      float p2 = S[8] * kk2.x + S[9] * kk2.y + S[10] * kk2.z + S[11] * kk2.w;
      float p3 = S[12] * kk3.x + S[13] * kk3.y + S[14] * kk3.z + S[15] * kk3.w;
      float sab = qadd12((p0 + p1) + (p2 + p3));
      float4 ew0 = *(const float4*)&lds[1][tb];
      float4 ew1 = *(const float4*)&lds[1][tb + 4];
      float4 ew2 = *(const float4*)&lds[1][tb + 8];
      float4 ew3 = *(const float4*)&lds[1][tb + 12];
      float4 bb0 = *(const float4*)&lds[3][tb];
      float4 bb1 = *(const float4*)&lds[3][tb + 4];
      float4 bb2 = *(const float4*)&lds[3][tb + 8];
      float4 bb3 = *(const float4*)&lds[3][tb + 12];
      float4 k0 = *(const float4*)&lds[2][tb];
      float4 k1 = *(const float4*)&lds[2][tb + 4];
      float4 k2 = *(const float4*)&lds[2][tb + 8];
      float4 k3 = *(const float4*)&lds[2][tb + 12];
      S[0] = S[0] * ew0.x + sab * bb0.x + cv * k0.x;
      S[1] = S[1] * ew0.y + sab * bb0.y + cv * k0.y;
      S[2] = S[2] * ew0.z + sab * bb0.z + cv * k0.z;
      S[3] = S[3] * ew0.w + sab * bb0.w + cv * k0.w;
      S[4] = S[4] * ew1.x + sab * bb1.x + cv * k1.x;
      S[5] = S[5] * ew1.y + sab * bb1.y + cv * k1.y;
      S[6] = S[6] * ew1.z + sab * bb1.z + cv * k1.z;
      S[7] = S[7] * ew1.w + sab * bb1.w + cv * k1.w;
      S[8] = S[8] * ew2.x + sab * bb2.x + cv * k2.x;
      S[9] = S[9] * ew2.y + sab * bb2.y + cv * k2.y;
      S[10] = S[10] * ew2.z + sab * bb2.z + cv * k2.z;
      S[11] = S[11] * ew2.w + sab * bb2.w + cv * k2.w;
      S[12] = S[12] * ew3.x + sab * bb3.x + cv * k3.x;
      S[13] = S[13] * ew3.y + sab * bb3.y + cv * k3.y;
      S[14] = S[14] * ew3.z + sab * bb3.z + cv * k3.z;
      S[15] = S[15] * ew3.w + sab * bb3.w + cv * k3.w;
      float4 r0 = *(const float4*)&lds[4][tb];
      float4 r1 = *(const float4*)&lds[4][tb + 4];
      float4 r2 = *(const float4*)&lds[4][tb + 8];
      float4 r3 = *(const float4*)&lds[4][tb + 12];
      float y0 = S[0] * r0.x + S[1] * r0.y + S[2] * r0.z + S[3] * r0.w;
      float y1 = S[4] * r1.x + S[5] * r1.y + S[6] * r1.z + S[7] * r1.w;
      float y2 = S[8] * r2.x + S[9] * r2.y + S[10] * r2.z + S[11] * r2.w;
      float y3 = S[12] * r3.x + S[13] * r3.y + S[14] * r3.z + S[15] * r3.w;
      float y = qadd12((y0 + y1) + (y2 + y3));
      if (q == 0) yB[base + (long)((c << 4) + tt) * C_ + row] = y;
    }
  }
}

// ---------------- K7: GroupNorm + bonus + gate (bf16 out) -------------------
__global__ __launch_bounds__(256) void gnout_kernel(
    const float* __restrict__ y, const float* __restrict__ r,
    const float* __restrict__ kf, const float* __restrict__ v,
    const float* __restrict__ g,
    const float* __restrict__ lnw, const float* __restrict__ lnb,
    const float* __restrict__ fa, bf16* __restrict__ z) {
  int tid = threadIdx.x;
  int w = tid >> 6, lane = tid & 63;
  int gi = (blockIdx.x << 2) + w;  // (b*T+t)*H + h
  int h = gi & 15, mt = gi >> 4;
  long off = (long)mt * C_ + (h << 6) + lane;
  float yv = y[off];
  float s = yv;
  s += __shfl_xor(s, 1); s += __shfl_xor(s, 2); s += __shfl_xor(s, 4);
  s += __shfl_xor(s, 8); s += __shfl_xor(s, 16); s += __shfl_xor(s, 32);
  float mu = s * (1.0f / 64.0f);
  float d = yv - mu;
  float s2 = d * d;
  s2 += __shfl_xor(s2, 1); s2 += __shfl_xor(s2, 2); s2 += __shfl_xor(s2, 4);
  s2 += __shfl_xor(s2, 8); s2 += __shfl_xor(s2, 16); s2 += __shfl_xor(s2, 32);
  float var = s2 * (1.0f / 64.0f);
  int hc = (h << 6) + lane;
  float dot = r[off] * kf[off] * fa[hc];
  dot += __shfl_xor(dot, 1); dot += __shfl_xor(dot, 2); dot += __shfl_xor(dot, 4);
  dot += __shfl_xor(dot, 8); dot += __shfl_xor(dot, 16); dot += __shfl_xor(dot, 32);
  float yn = d * rsqrtf(var + 0.00064f) * lnw[hc] + lnb[hc];
  z[off] = f2bf((yn + dot * v[off]) * g[off]);
}

extern "C" void kernel_launch(void* const* d_in, const int* in_sizes, int n_in,
                              void* d_out, int out_size, void* d_ws, size_t ws_size,
                              hipStream_t stream) {
  const float* x = (const float*)d_in[0];
  const float* tmx = (const float*)d_in[1];
  const float* tmaa = (const float*)d_in[2];
  const float* tmw1 = (const float*)d_in[3];
  const float* tmw2 = (const float*)d_in[4];
  const float* tdec = (const float*)d_in[5];
  const float* tdw1 = (const float*)d_in[6];
  const float* tdw2 = (const float*)d_in[7];
  const float* taa5 = (const float*)d_in[8];
  const float* taw1 = (const float*)d_in[9];
  const float* taw2 = (const float*)d_in[10];
  const float* tkw1 = (const float*)d_in[11];
  const float* tkw2 = (const float*)d_in[12];
  const float* gw1 = (const float*)d_in[13];
  const float* gw2 = (const float*)d_in[14];
  const float* tmia = (const float*)d_in[15];
  const float* maw1 = (const float*)d_in[16];
  const float* maw2 = (const float*)d_in[17];
  const float* tmik = (const float*)d_in[18];
  const float* mkw1 = (const float*)d_in[19];
  const float* mkw2 = (const float*)d_in[20];
  const float* wrec = (const float*)d_in[21];
  const float* wkey = (const float*)d_in[22];
  const float* wval = (const float*)d_in[23];
  const float* wout = (const float*)d_in[24];
  const float* lnw = (const float*)d_in[25];
  const float* lnb = (const float*)d_in[26];
  const float* faaa = (const float*)d_in[27];

  const long MT = 2048, CC = 1024;
  char* base = (char*)d_ws;
  float* xx = (float*)base;    base += MT * CC * 4;   // also y
  bf16* xxxb = (bf16*)base;    base += MT * CC * 2;
  bf16* xrgb = (bf16*)base;    base += MT * CC * 2;   // ┐ kfin overlays (8MB)
  bf16* xwab = (bf16*)base;    base += MT * CC * 2;   // ┘
  bf16* xkb = (bf16*)base;     base += MT * CC * 2;   // ┐ kkn overlays (8MB)
  bf16* xvb = (bf16*)base;     base += MT * CC * 2;   // ┘
  float* rr = (float*)base;    base += MT * CC * 4;
  float* kraw = (float*)base;  base += MT * CC * 4;   // also ew
  float* vv = (float*)base;    base += MT * CC * 4;
  float* gg = (float*)base;    base += MT * CC * 4;
  float* bbo = (float*)base;   base += MT * CC * 4;
  float* mix = (float*)base;   base += MT * 128 * 4;
  bf16* g1b = (bf16*)base;     base += MT * 128 * 2;
  float* out1 = (float*)base;  base += MT * 32 * 4;   // [kk1|mk1]
  float* out2 = (float*)base;  base += MT * 96 * 4;   // [w1|a1|ma1]
  bf16* zb = (bf16*)base;      base += MT * CC * 2;
  bf16* tmw1b = (bf16*)base;   base += 128 * CC * 2;
  bf16* wrecb = (bf16*)base;   base += CC * CC * 2;
  bf16* gw1b = (bf16*)base;    base += 128 * CC * 2;
  bf16* gw2b = (bf16*)base;    base += CC * 128 * 2;
  bf16* wkeyb = (bf16*)base;   base += CC * CC * 2;
  bf16* wvalb = (bf16*)base;   base += CC * CC * 2;
  bf16* woutb = (bf16*)base;   base += CC * CC * 2;
  bf16* wskb = (bf16*)base;    base += 32 * CC * 2;
  bf16* wswab = (bf16*)base;   base += 96 * CC * 2;
  bf16* tmw2b = (bf16*)base;   base += 4 * CC * 32 * 2;
  bf16* tdw2b = (bf16*)base;   base += CC * 64 * 2;
  bf16* tkw2b = (bf16*)base;   base += CC * 16 * 2;
  bf16* taw2b = (bf16*)base;   base += CC * 16 * 2;
  bf16* maw2b = (bf16*)base;   base += CC * 16 * 2;
  bf16* mkw2b = (bf16*)base;   base += CC * 16 * 2;
  // aliases (dead-buffer reuse, verified non-overlapping in time):
  float* ew = kraw;            // fuse2 reads kraw then writes ew at same offs
  float* kfin = (float*)xrgb;  // xrg/xwa bf16 dead before fuse2
  float* kkn = (float*)xkb;    // xk/xv bf16 dead before fuse2
  float* y = xx;               // xx dead after mix4

  auto gemm_m = [&](const bf16* A, const bf16* W, float* Cf, bf16* Cb,
                    int M, int N, int K, int actN) {
    dim3 grid((N + 63) / 64, M / 64);
    gemm_mfma_kernel<<<grid, 256, 0, stream>>>(A, W, Cf, Cb, M, N, K, actN);
  };

  cvt_weights_kernel<<<4480, 256, 0, stream>>>(
      tmw1, wrec, gw1, gw2, wkey, wval, wout,
      tmw1b, wrecb, gw1b, gw2b, wkeyb, wvalb, woutb);
  cvt_small_kernel<<<128, 256, 0, stream>>>(tkw1, mkw1, tdw1, taw1, maw1,
                                            wskb, wswab);
  cvt_small2_kernel<<<256, 256, 0, stream>>>(tmw2, tdw2, tkw2, taw2, maw2, mkw2,
                                             tmw2b, tdw2b, tkw2b, taw2b,
                                             maw2b, mkw2b);
  shift_kernel<<<8192, 256, 0, stream>>>(x, tmx, xx, xxxb);
  gemm_m(xxxb, tmw1b, mix, nullptr, 2048, 128, 1024, 128);   // tanh all
  mix4_kernel<<<2048, 256, 0, stream>>>(x, xx, mix, tmaa, tmw2b,
                                        xrgb, xwab, xkb, xvb);
  gemm_m(xrgb, wrecb, rr, nullptr, 2048, 1024, 1024, 0);
  gemm_m(xrgb, gw1b, nullptr, g1b, 2048, 128, 1024, 128);    // tanh all
  gemm_m(g1b, gw2b, gg, nullptr, 2048, 1024, 128, 0);
  gemm_m(xkb, wkeyb, kraw, nullptr, 2048, 1024, 1024, 0);
  gemm_m(xkb, wskb, out1, nullptr, 2048, 32, 1024, 16);      // tanh cols<16
  gemm_m(xvb, wvalb, vv, nullptr, 2048, 1024, 1024, 0);
  gemm_m(xwab, wswab, out2, nullptr, 2048, 96, 1024, 64);    // tanh cols<64
  fuse2_kernel<<<2048, 256, 0, stream>>>(kraw, out1, out2,
                                         tdw2b, tkw2b, taw2b, maw2b, mkw2b,
                                         tdec, taa5, tmia, tmik,
                                         ew, kfin, kkn, bbo);
  scan_kernel<<<32, 256, 0, stream>>>(rr, ew, kfin, vv, kkn, bbo, y);
  gnout_kernel<<<8192, 256, 0, stream>>>(y, rr, kfin, vv, gg, lnw, lnb, faaa, zb);
  gemm_m(zb, woutb, (float*)d_out, nullptr, 2048, 1024, 1024, 0);
}

// Round 12
// 828.276 us; speedup vs baseline: 1.1887x; 1.0536x over previous
//
#include <hip/hip_runtime.h>
#include <hip/hip_bf16.h>

typedef __hip_bfloat16 bf16;

#define B_ 2
#define T_ 1024
#define C_ 1024
#define H_ 16
#define N_ 64

using short8 = __attribute__((ext_vector_type(8))) short;
using f32x4 = __attribute__((ext_vector_type(4))) float;

__device__ __forceinline__ float us2f(unsigned short u) {
  return __uint_as_float(((unsigned int)u) << 16);
}
__device__ __forceinline__ float bs2f(short s) {
  return __uint_as_float(((unsigned int)(unsigned short)s) << 16);
}
__device__ __forceinline__ bf16 f2bf(float f) { return __float2bfloat16(f); }
__device__ __forceinline__ float sigmoidf_(float x) { return 1.0f / (1.0f + expf(-x)); }
__device__ __forceinline__ float softplusf_(float x) {
  return fmaxf(x, 0.0f) + log1pf(expf(-fabsf(x)));
}
// Full 16-lane-row sum, all lanes receive the result. Pure-VALU DPP:
// quad_perm xor1, xor2 give quad sums (period-4 pattern within the 16-lane
// row); row_ror:4 + row_ror:8 rotate-adds then complete the sum exactly.
__device__ __forceinline__ float qsum16(float x) {
  int a = __builtin_amdgcn_update_dpp(0, __float_as_int(x), 0xB1, 0xF, 0xF, true);
  x += __int_as_float(a);                       // quad_perm [1,0,3,2] (xor 1)
  int b = __builtin_amdgcn_update_dpp(0, __float_as_int(x), 0x4E, 0xF, 0xF, true);
  x += __int_as_float(b);                       // quad_perm [2,3,0,1] (xor 2)
  int c = __builtin_amdgcn_update_dpp(0, __float_as_int(x), 0x124, 0xF, 0xF, true);
  x += __int_as_float(c);                       // row_ror:4
  int d = __builtin_amdgcn_update_dpp(0, __float_as_int(x), 0x128, 0xF, 0xF, true);
  x += __int_as_float(d);                       // row_ror:8
  return x;
}

// ---------------- K0: fused weight fp32->bf16 conversion (big weights) ------
__global__ __launch_bounds__(256) void cvt_weights_kernel(
    const float* __restrict__ s0, const float* __restrict__ s1,
    const float* __restrict__ s2, const float* __restrict__ s3,
    const float* __restrict__ s4, const float* __restrict__ s5,
    const float* __restrict__ s6,
    bf16* __restrict__ d0, bf16* __restrict__ d1, bf16* __restrict__ d2,
    bf16* __restrict__ d3, bf16* __restrict__ d4, bf16* __restrict__ d5,
    bf16* __restrict__ d6) {
  long i4 = (long)blockIdx.x * 256 + threadIdx.x;
  const float* s; bf16* d; long off;
  if (i4 < 32768) { s = s0; d = d0; off = i4; }
  else if (i4 < 294912) { s = s1; d = d1; off = i4 - 32768; }
  else if (i4 < 327680) { s = s2; d = d2; off = i4 - 294912; }
  else if (i4 < 360448) { s = s3; d = d3; off = i4 - 327680; }
  else if (i4 < 622592) { s = s4; d = d4; off = i4 - 360448; }
  else if (i4 < 884736) { s = s5; d = d5; off = i4 - 622592; }
  else { s = s6; d = d6; off = i4 - 884736; }
  float4 v = *(const float4*)(s + off * 4);
  d[off * 4 + 0] = f2bf(v.x);
  d[off * 4 + 1] = f2bf(v.y);
  d[off * 4 + 2] = f2bf(v.z);
  d[off * 4 + 3] = f2bf(v.w);
}

// ---------------- K0b: pack small LoRA-1 weights to bf16 --------------------
__global__ __launch_bounds__(256) void cvt_small_kernel(
    const float* __restrict__ tkw1, const float* __restrict__ mkw1,
    const float* __restrict__ tdw1, const float* __restrict__ taw1,
    const float* __restrict__ maw1,
    bf16* __restrict__ wsk, bf16* __restrict__ wswa) {
  long i4 = (long)blockIdx.x * 256 + threadIdx.x;  // < 32768
  const float* s; bf16* d; long so, dof;
  if (i4 < 4096) { s = tkw1; so = i4; d = wsk; dof = i4; }
  else if (i4 < 8192) { s = mkw1; so = i4 - 4096; d = wsk; dof = i4; }
  else if (i4 < 24576) { s = tdw1; so = i4 - 8192; d = wswa; dof = i4 - 8192; }
  else if (i4 < 28672) { s = taw1; so = i4 - 24576; d = wswa; dof = i4 - 8192; }
  else { s = maw1; so = i4 - 28672; d = wswa; dof = i4 - 8192; }
  float4 v = *(const float4*)(s + so * 4);
  d[dof * 4 + 0] = f2bf(v.x);
  d[dof * 4 + 1] = f2bf(v.y);
  d[dof * 4 + 2] = f2bf(v.z);
  d[dof * 4 + 3] = f2bf(v.w);
}

// ---------------- K0c: LoRA-2 weights to bf16 -------------------------------
__global__ __launch_bounds__(256) void cvt_small2_kernel(
    const float* __restrict__ tmw2, const float* __restrict__ tdw2,
    const float* __restrict__ tkw2, const float* __restrict__ taw2,
    const float* __restrict__ maw2, const float* __restrict__ mkw2,
    bf16* __restrict__ tmw2b, bf16* __restrict__ tdw2b,
    bf16* __restrict__ tkw2b, bf16* __restrict__ taw2b,
    bf16* __restrict__ maw2b, bf16* __restrict__ mkw2b) {
  long i4 = (long)blockIdx.x * 256 + threadIdx.x;  // < 65536
  const float* s; bf16* d; long off;
  if (i4 < 32768) { s = tmw2; d = tmw2b; off = i4; }
  else if (i4 < 49152) { s = tdw2; d = tdw2b; off = i4 - 32768; }
  else if (i4 < 53248) { s = tkw2; d = tkw2b; off = i4 - 49152; }
  else if (i4 < 57344) { s = taw2; d = taw2b; off = i4 - 53248; }
  else if (i4 < 61440) { s = maw2; d = maw2b; off = i4 - 57344; }
  else { s = mkw2; d = mkw2b; off = i4 - 61440; }
  float4 v = *(const float4*)(s + off * 4);
  d[off * 4 + 0] = f2bf(v.x);
  d[off * 4 + 1] = f2bf(v.y);
  d[off * 4 + 2] = f2bf(v.z);
  d[off * 4 + 3] = f2bf(v.w);
}

// ---------------- K1: token shift (writes xx f32, xxx bf16) -----------------
__global__ __launch_bounds__(256) void shift_kernel(
    const float* __restrict__ x, const float* __restrict__ tmx,
    float* __restrict__ xx, bf16* __restrict__ xxxb) {
  long idx = (long)blockIdx.x * 256 + threadIdx.x;  // < B*T*C
  int c = (int)(idx & (C_ - 1));
  int t = (int)((idx >> 10) & (T_ - 1));
  float xv = x[idx];
  float xp = (t > 0) ? x[idx - C_] : 0.0f;
  float d = xp - xv;
  xx[idx] = d;
  xxxb[idx] = f2bf(xv + d * tmx[c]);
}

// ---------------- MFMA GEMM: C = A(bf16 MxK) * W^T (W bf16 NxK) -------------
__global__ __launch_bounds__(256) void gemm_mfma_kernel(
    const bf16* __restrict__ A, const bf16* __restrict__ W,
    float* __restrict__ Cf, bf16* __restrict__ Cb,
    int M, int N, int K, int actN) {
  __shared__ __align__(16) bf16 As[64][72];  // 144B row stride, 16B aligned
  __shared__ __align__(16) bf16 Ws[64][72];
  int tid = threadIdx.x;
  int m0 = blockIdx.y << 6, n0 = blockIdx.x << 6;
  int srow = tid >> 2, skg = (tid & 3) << 4;   // staging: row, 16 bf16 per thread
  int wv = tid >> 6, lane = tid & 63;
  int fr = lane & 15, fq = lane >> 4;
  f32x4 acc0 = {0.f, 0.f, 0.f, 0.f}, acc1 = acc0, acc2 = acc0, acc3 = acc0;
  bool wok = (n0 + srow) < N;
  const bf16* Ap = A + (long)(m0 + srow) * K + skg;
  const bf16* Wp = W + (long)(n0 + srow) * K + skg;
  short8 zz = {0, 0, 0, 0, 0, 0, 0, 0};
  for (int k0 = 0; k0 < K; k0 += 64) {
    *(short8*)&As[srow][skg] = *(const short8*)(Ap + k0);
    *(short8*)&As[srow][skg + 8] = *(const short8*)(Ap + k0 + 8);
    *(short8*)&Ws[srow][skg] = wok ? *(const short8*)(Wp + k0) : zz;
    *(short8*)&Ws[srow][skg + 8] = wok ? *(const short8*)(Wp + k0 + 8) : zz;
    __syncthreads();
#pragma unroll
    for (int kk = 0; kk < 2; kk++) {
      int ko = (fq << 3) + (kk << 5);
      short8 af = *(const short8*)&As[(wv << 4) + fr][ko];
      short8 b0 = *(const short8*)&Ws[fr][ko];
      short8 b1 = *(const short8*)&Ws[16 + fr][ko];
      short8 b2 = *(const short8*)&Ws[32 + fr][ko];
      short8 b3 = *(const short8*)&Ws[48 + fr][ko];
      acc0 = __builtin_amdgcn_mfma_f32_16x16x32_bf16(af, b0, acc0, 0, 0, 0);
      acc1 = __builtin_amdgcn_mfma_f32_16x16x32_bf16(af, b1, acc1, 0, 0, 0);
      acc2 = __builtin_amdgcn_mfma_f32_16x16x32_bf16(af, b2, acc2, 0, 0, 0);
      acc3 = __builtin_amdgcn_mfma_f32_16x16x32_bf16(af, b3, acc3, 0, 0, 0);
    }
    __syncthreads();
  }
  int orow = m0 + (wv << 4) + (fq << 2);
  int ocol = n0 + fr;
  f32x4 av[4] = {acc0, acc1, acc2, acc3};
#pragma unroll
  for (int nt = 0; nt < 4; nt++) {
    int col = ocol + (nt << 4);
    if (col < N) {
#pragma unroll
      for (int r = 0; r < 4; r++) {
        float vvv = av[nt][r];
        if (col < actN) vvv = tanhf(vvv);
        long oi = (long)(orow + r) * N + col;
        if (Cb) Cb[oi] = f2bf(vvv); else Cf[oi] = vvv;
      }
    }
  }
}

// ---------------- K3: deltas + build xrg/xwa/xk/xv (bf16 out) ---------------
__global__ __launch_bounds__(256) void mix4_kernel(
    const float* __restrict__ x, const float* __restrict__ xx,
    const float* __restrict__ mix, const float* __restrict__ tmaa,
    const bf16* __restrict__ w2b,
    bf16* __restrict__ xrg, bf16* __restrict__ xwa,
    bf16* __restrict__ xk, bf16* __restrict__ xv) {
  int m = blockIdx.x;
  int tid = threadIdx.x;
  __shared__ float mrow[128];
  if (tid < 128) mrow[tid] = mix[(long)m * 128 + tid];
  __syncthreads();
#pragma unroll
  for (int cc = 0; cc < 4; cc++) {
    int c = tid + (cc << 8);
    long off = (long)m * C_ + c;
    float xb = x[off];
    float xxv = xx[off];
    float res[4];
#pragma unroll
    for (int f = 0; f < 4; f++) {
      const short8* wp = (const short8*)(w2b + (((long)f * C_ + c) << 5));
      float dl = 0.f;
#pragma unroll
      for (int d8 = 0; d8 < 4; d8++) {
        short8 u = wp[d8];
        int db = (f << 5) + (d8 << 3);
#pragma unroll
        for (int e = 0; e < 8; e++) dl += mrow[db + e] * bs2f(u[e]);
      }
      res[f] = xb + xxv * (tmaa[f * C_ + c] + dl);
    }
    xrg[off] = f2bf(res[0]); xwa[off] = f2bf(res[1]);
    xk[off] = f2bf(res[2]); xv[off] = f2bf(res[3]);
  }
}

// ---------------- K5: stage-2 small GEMMs + gates + per-head kk norm --------
__global__ __launch_bounds__(256) void fuse2_kernel(
    const float* __restrict__ kraw, const float* __restrict__ out1,
    const float* __restrict__ out2,
    const bf16* __restrict__ dw2, const bf16* __restrict__ kkw2,
    const bf16* __restrict__ aw2, const bf16* __restrict__ maw2,
    const bf16* __restrict__ mkw2,
    const float* __restrict__ tdec, const float* __restrict__ taa,
    const float* __restrict__ tma, const float* __restrict__ tmk,
    float* __restrict__ ew, float* __restrict__ kfin,
    float* __restrict__ kkn, float* __restrict__ bbo) {
  int m = blockIdx.x, tid = threadIdx.x;
  __shared__ float w1r[64], kk1r[16], a1r[16], ma1r[16], mk1r[16];
  if (tid < 64) w1r[tid] = out2[(long)m * 96 + tid];
  else if (tid < 80) kk1r[tid - 64] = out1[(long)m * 32 + (tid - 64)];
  else if (tid < 96) a1r[tid - 80] = out2[(long)m * 96 + 64 + (tid - 80)];
  else if (tid < 112) ma1r[tid - 96] = out2[(long)m * 96 + 80 + (tid - 96)];
  else if (tid < 128) mk1r[tid - 112] = out1[(long)m * 32 + 16 + (tid - 112)];
  __syncthreads();
  float kkp[4], av[4], wv[4], kr[4], mkv[4];
  float sumsq = 0.f;
#pragma unroll
  for (int j = 0; j < 4; j++) {
    int c = (tid << 2) + j;
    long off = (long)m * C_ + c;
    float wd = 0.f;
    const short8* dp = (const short8*)(dw2 + ((long)c << 6));
#pragma unroll
    for (int d8 = 0; d8 < 8; d8++) {
      short8 u = dp[d8];
      int db = d8 << 3;
#pragma unroll
      for (int e = 0; e < 8; e++) wd += w1r[db + e] * bs2f(u[e]);
    }
    float w = -softplusf_(-(tdec[c] + wd)) - 0.5f;
    wv[j] = w;
    float kd = 0.f, ad = 0.f, mad = 0.f, mkd = 0.f;
    const short8* kp = (const short8*)(kkw2 + ((long)c << 4));
    const short8* ap = (const short8*)(aw2 + ((long)c << 4));
    const short8* mp = (const short8*)(maw2 + ((long)c << 4));
    const short8* qp = (const short8*)(mkw2 + ((long)c << 4));
#pragma unroll
    for (int d8 = 0; d8 < 2; d8++) {
      short8 u1 = kp[d8], u2 = ap[d8], u3 = mp[d8], u4 = qp[d8];
      int db = d8 << 3;
#pragma unroll
      for (int e = 0; e < 8; e++) {
        kd += kk1r[db + e] * bs2f(u1[e]);
        ad += a1r[db + e] * bs2f(u2[e]);
        mad += ma1r[db + e] * bs2f(u3[e]);
        mkd += mk1r[db + e] * bs2f(u4[e]);
      }
    }
    float krw = kraw[off];
    float kkpre = krw + kd;
    kkp[j] = kkpre;
    sumsq += kkpre * kkpre;
    float a = sigmoidf_(taa[c] + ad);
    av[j] = a;
    float ma = sigmoidf_(tma[c] + mad);
    float mk = sigmoidf_(tmk[c] + mkd);
    mkv[j] = mk;
    kr[j] = krw * (ma + a * (1.f - ma));
  }
  sumsq += __shfl_xor(sumsq, 1);
  sumsq += __shfl_xor(sumsq, 2);
  sumsq += __shfl_xor(sumsq, 4);
  sumsq += __shfl_xor(sumsq, 8);
  float rn = 1.0f / fmaxf(sqrtf(sumsq), 1e-12f);
#pragma unroll
  for (int j = 0; j < 4; j++) {
    int c = (tid << 2) + j;
    long off = (long)m * C_ + c;
    float kknv = kkp[j] * rn;
    kkn[off] = kknv;
    bbo[off] = -kknv * av[j];
    ew[off] = expf(wv[j]);
    kfin[off] = kr[j] * expf(wv[j] * mkv[j]);
  }
}

// ---------------- K6: RWKV-7 scan, cooperative block per (b,h) --------------
// 32 blocks x 256 threads. Wave w = rowgroup w (rows w*16..w*16+15). LDS
// staging as round 10/11 (perfect dedup). NEW lane layout: lane = g*16+q
// (g=lane>>4, q=lane&15); each lane owns 4 rows (w*16+g*4+j) x 4 keys
// (4q..4q+3) -> 6 ds_read_b128 per token (was 21). Reductions over the
// 16-lane row via qsum16 (quad_perm + row_ror DPP, pure VALU).
#define SCHUNK 16
__global__ __launch_bounds__(256) void scan_kernel(
    const float* __restrict__ rB, const float* __restrict__ ewB,
    const float* __restrict__ kB, const float* __restrict__ vB,
    const float* __restrict__ kkB, const float* __restrict__ bbB,
    float* __restrict__ yB) {
  __shared__ __align__(16) float lds[6][SCHUNK * 64];
  int bh = blockIdx.x;           // 0..31
  int b = bh >> 4, h = bh & 15;
  int tid = threadIdx.x;
  int wave = tid >> 6, lane = tid & 63;
  int g = lane >> 4, q = lane & 15;
  int rowbase = (wave << 4) + (g << 2);   // 4 rows: rowbase..rowbase+3
  int kq = q << 2;                        // 4 keys: kq..kq+3
  const long base = ((long)b * T_) * C_ + (h << 6);
  const float* s0 = kkB + base;
  const float* s1 = ewB + base;
  const float* s2 = kB + base;
  const float* s3 = bbB + base;
  const float* s4 = rB + base;
  const float* s5 = vB + base;
  int stok = tid >> 4;           // staging token within chunk (0..15)
  int spc = (tid & 15) << 2;     // float offset within token row
  int lo = (stok << 6) + spc;    // LDS float offset
  float4 rb0, rb1, rb2, rb3, rb4, rb5;
  auto loadc = [&](int c) {
    long go = (long)((c << 4) + stok) * C_ + spc;
    rb0 = *(const float4*)(s0 + go);
    rb1 = *(const float4*)(s1 + go);
    rb2 = *(const float4*)(s2 + go);
    rb3 = *(const float4*)(s3 + go);
    rb4 = *(const float4*)(s4 + go);
    rb5 = *(const float4*)(s5 + go);
  };
  float S[16];  // S[j*4+m]: row rowbase+j, key kq+m
#pragma unroll
  for (int j = 0; j < 16; j++) S[j] = 0.f;
  loadc(0);
  for (int c = 0; c < T_ / SCHUNK; c++) {
    __syncthreads();
    *(float4*)&lds[0][lo] = rb0;
    *(float4*)&lds[1][lo] = rb1;
    *(float4*)&lds[2][lo] = rb2;
    *(float4*)&lds[3][lo] = rb3;
    *(float4*)&lds[4][lo] = rb4;
    *(float4*)&lds[5][lo] = rb5;
    __syncthreads();
    if (c + 1 < T_ / SCHUNK) loadc(c + 1);
#pragma unroll 8
    for (int tt = 0; tt < SCHUNK; tt++) {
      int tb = tt << 6;
      float4 kk = *(const float4*)&lds[0][tb + kq];
      float4 vv = *(const float4*)&lds[5][tb + rowbase];
      float p0 = S[0] * kk.x + S[1] * kk.y + S[2] * kk.z + S[3] * kk.w;
      float p1 = S[4] * kk.x + S[5] * kk.y + S[6] * kk.z + S[7] * kk.w;
      float p2 = S[8] * kk.x + S[9] * kk.y + S[10] * kk.z + S[11] * kk.w;
      float p3 = S[12] * kk.x + S[13] * kk.y + S[14] * kk.z + S[15] * kk.w;
      float sab0 = qsum16(p0);
      float sab1 = qsum16(p1);
      float sab2 = qsum16(p2);
      float sab3 = qsum16(p3);
      float4 ew = *(const float4*)&lds[1][tb + kq];
      float4 bb = *(const float4*)&lds[3][tb + kq];
      float4 k4 = *(const float4*)&lds[2][tb + kq];
      S[0] = S[0] * ew.x + sab0 * bb.x + vv.x * k4.x;
      S[1] = S[1] * ew.y + sab0 * bb.y + vv.x * k4.y;
      S[2] = S[2] * ew.z + sab0 * bb.z + vv.x * k4.z;
      S[3] = S[3] * ew.w + sab0 * bb.w + vv.x * k4.w;
      S[4] = S[4] * ew.x + sab1 * bb.x + vv.y * k4.x;
      S[5] = S[5] * ew.y + sab1 * bb.y + vv.y * k4.y;
      S[6] = S[6] * ew.z + sab1 * bb.z + vv.y * k4.z;
      S[7] = S[7] * ew.w + sab1 * bb.w + vv.y * k4.w;
      S[8] = S[8] * ew.x + sab2 * bb.x + vv.z * k4.x;
      S[9] = S[9] * ew.y + sab2 * bb.y + vv.z * k4.y;
      S[10] = S[10] * ew.z + sab2 * bb.z + vv.z * k4.z;
      S[11] = S[11] * ew.w + sab2 * bb.w + vv.z * k4.w;
      S[12] = S[12] * ew.x + sab3 * bb.x + vv.w * k4.x;
      S[13] = S[13] * ew.y + sab3 * bb.y + vv.w * k4.y;
      S[14] = S[14] * ew.z + sab3 * bb.z + vv.w * k4.w * 0.f + vv.w * k4.z;
      S[15] = S[15] * ew.w + sab3 * bb.w + vv.w * k4.w;
      float4 r4 = *(const float4*)&lds[4][tb + kq];
      float y0 = S[0] * r4.x + S[1] * r4.y + S[2] * r4.z + S[3] * r4.w;
      float y1 = S[4] * r4.x + S[5] * r4.y + S[6] * r4.z + S[7] * r4.w;
      float y2 = S[8] * r4.x + S[9] * r4.y + S[10] * r4.z + S[11] * r4.w;
      float y3 = S[12] * r4.x + S[13] * r4.y + S[14] * r4.z + S[15] * r4.w;
      y0 = qsum16(y0);
      y1 = qsum16(y1);
      y2 = qsum16(y2);
      y3 = qsum16(y3);
      if (q == 0) {
        float4 yo = make_float4(y0, y1, y2, y3);
        *(float4*)(yB + base + (long)((c << 4) + tt) * C_ + rowbase) = yo;
      }
    }
  }
}

// ---------------- K7: GroupNorm + bonus + gate (bf16 out) -------------------
__global__ __launch_bounds__(256) void gnout_kernel(
    const float* __restrict__ y, const float* __restrict__ r,
    const float* __restrict__ kf, const float* __restrict__ v,
    const float* __restrict__ g,
    const float* __restrict__ lnw, const float* __restrict__ lnb,
    const float* __restrict__ fa, bf16* __restrict__ z) {
  int tid = threadIdx.x;
  int w = tid >> 6, lane = tid & 63;
  int gi = (blockIdx.x << 2) + w;  // (b*T+t)*H + h
  int h = gi & 15, mt = gi >> 4;
  long off = (long)mt * C_ + (h << 6) + lane;
  float yv = y[off];
  float s = yv;
  s += __shfl_xor(s, 1); s += __shfl_xor(s, 2); s += __shfl_xor(s, 4);
  s += __shfl_xor(s, 8); s += __shfl_xor(s, 16); s += __shfl_xor(s, 32);
  float mu = s * (1.0f / 64.0f);
  float d = yv - mu;
  float s2 = d * d;
  s2 += __shfl_xor(s2, 1); s2 += __shfl_xor(s2, 2); s2 += __shfl_xor(s2, 4);
  s2 += __shfl_xor(s2, 8); s2 += __shfl_xor(s2, 16); s2 += __shfl_xor(s2, 32);
  float var = s2 * (1.0f / 64.0f);
  int hc = (h << 6) + lane;
  float dot = r[off] * kf[off] * fa[hc];
  dot += __shfl_xor(dot, 1); dot += __shfl_xor(dot, 2); dot += __shfl_xor(dot, 4);
  dot += __shfl_xor(dot, 8); dot += __shfl_xor(dot, 16); dot += __shfl_xor(dot, 32);
  float yn = d * rsqrtf(var + 0.00064f) * lnw[hc] + lnb[hc];
  z[off] = f2bf((yn + dot * v[off]) * g[off]);
}

extern "C" void kernel_launch(void* const* d_in, const int* in_sizes, int n_in,
                              void* d_out, int out_size, void* d_ws, size_t ws_size,
                              hipStream_t stream) {
  const float* x = (const float*)d_in[0];
  const float* tmx = (const float*)d_in[1];
  const float* tmaa = (const float*)d_in[2];
  const float* tmw1 = (const float*)d_in[3];
  const float* tmw2 = (const float*)d_in[4];
  const float* tdec = (const float*)d_in[5];
  const float* tdw1 = (const float*)d_in[6];
  const float* tdw2 = (const float*)d_in[7];
  const float* taa5 = (const float*)d_in[8];
  const float* taw1 = (const float*)d_in[9];
  const float* taw2 = (const float*)d_in[10];
  const float* tkw1 = (const float*)d_in[11];
  const float* tkw2 = (const float*)d_in[12];
  const float* gw1 = (const float*)d_in[13];
  const float* gw2 = (const float*)d_in[14];
  const float* tmia = (const float*)d_in[15];
  const float* maw1 = (const float*)d_in[16];
  const float* maw2 = (const float*)d_in[17];
  const float* tmik = (const float*)d_in[18];
  const float* mkw1 = (const float*)d_in[19];
  const float* mkw2 = (const float*)d_in[20];
  const float* wrec = (const float*)d_in[21];
  const float* wkey = (const float*)d_in[22];
  const float* wval = (const float*)d_in[23];
  const float* wout = (const float*)d_in[24];
  const float* lnw = (const float*)d_in[25];
  const float* lnb = (const float*)d_in[26];
  const float* faaa = (const float*)d_in[27];

  const long MT = 2048, CC = 1024;
  char* base = (char*)d_ws;
  float* xx = (float*)base;    base += MT * CC * 4;   // also y
  bf16* xxxb = (bf16*)base;    base += MT * CC * 2;
  bf16* xrgb = (bf16*)base;    base += MT * CC * 2;   // ┐ kfin overlays (8MB)
  bf16* xwab = (bf16*)base;    base += MT * CC * 2;   // ┘
  bf16* xkb = (bf16*)base;     base += MT * CC * 2;   // ┐ kkn overlays (8MB)
  bf16* xvb = (bf16*)base;     base += MT * CC * 2;   // ┘
  float* rr = (float*)base;    base += MT * CC * 4;
  float* kraw = (float*)base;  base += MT * CC * 4;   // also ew
  float* vv = (float*)base;    base += MT * CC * 4;
  float* gg = (float*)base;    base += MT * CC * 4;
  float* bbo = (float*)base;   base += MT * CC * 4;
  float* mix = (float*)base;   base += MT * 128 * 4;
  bf16* g1b = (bf16*)base;     base += MT * 128 * 2;
  float* out1 = (float*)base;  base += MT * 32 * 4;   // [kk1|mk1]
  float* out2 = (float*)base;  base += MT * 96 * 4;   // [w1|a1|ma1]
  bf16* zb = (bf16*)base;      base += MT * CC * 2;
  bf16* tmw1b = (bf16*)base;   base += 128 * CC * 2;
  bf16* wrecb = (bf16*)base;   base += CC * CC * 2;
  bf16* gw1b = (bf16*)base;    base += 128 * CC * 2;
  bf16* gw2b = (bf16*)base;    base += CC * 128 * 2;
  bf16* wkeyb = (bf16*)base;   base += CC * CC * 2;
  bf16* wvalb = (bf16*)base;   base += CC * CC * 2;
  bf16* woutb = (bf16*)base;   base += CC * CC * 2;
  bf16* wskb = (bf16*)base;    base += 32 * CC * 2;
  bf16* wswab = (bf16*)base;   base += 96 * CC * 2;
  bf16* tmw2b = (bf16*)base;   base += 4 * CC * 32 * 2;
  bf16* tdw2b = (bf16*)base;   base += CC * 64 * 2;
  bf16* tkw2b = (bf16*)base;   base += CC * 16 * 2;
  bf16* taw2b = (bf16*)base;   base += CC * 16 * 2;
  bf16* maw2b = (bf16*)base;   base += CC * 16 * 2;
  bf16* mkw2b = (bf16*)base;   base += CC * 16 * 2;
  // aliases (dead-buffer reuse, verified non-overlapping in time):
  float* ew = kraw;            // fuse2 reads kraw then writes ew at same offs
  float* kfin = (float*)xrgb;  // xrg/xwa bf16 dead before fuse2
  float* kkn = (float*)xkb;    // xk/xv bf16 dead before fuse2
  float* y = xx;               // xx dead after mix4

  auto gemm_m = [&](const bf16* A, const bf16* W, float* Cf, bf16* Cb,
                    int M, int N, int K, int actN) {
    dim3 grid((N + 63) / 64, M / 64);
    gemm_mfma_kernel<<<grid, 256, 0, stream>>>(A, W, Cf, Cb, M, N, K, actN);
  };

  cvt_weights_kernel<<<4480, 256, 0, stream>>>(
      tmw1, wrec, gw1, gw2, wkey, wval, wout,
      tmw1b, wrecb, gw1b, gw2b, wkeyb, wvalb, woutb);
  cvt_small_kernel<<<128, 256, 0, stream>>>(tkw1, mkw1, tdw1, taw1, maw1,
                                            wskb, wswab);
  cvt_small2_kernel<<<256, 256, 0, stream>>>(tmw2, tdw2, tkw2, taw2, maw2, mkw2,
                                             tmw2b, tdw2b, tkw2b, taw2b,
                                             maw2b, mkw2b);
  shift_kernel<<<8192, 256, 0, stream>>>(x, tmx, xx, xxxb);
  gemm_m(xxxb, tmw1b, mix, nullptr, 2048, 128, 1024, 128);   // tanh all
  mix4_kernel<<<2048, 256, 0, stream>>>(x, xx, mix, tmaa, tmw2b,
                                        xrgb, xwab, xkb, xvb);
  gemm_m(xrgb, wrecb, rr, nullptr, 2048, 1024, 1024, 0);
  gemm_m(xrgb, gw1b, nullptr, g1b, 2048, 128, 1024, 128);    // tanh all
  gemm_m(g1b, gw2b, gg, nullptr, 2048, 1024, 128, 0);
  gemm_m(xkb, wkeyb, kraw, nullptr, 2048, 1024, 1024, 0);
  gemm_m(xkb, wskb, out1, nullptr, 2048, 32, 1024, 16);      // tanh cols<16
  gemm_m(xvb, wvalb, vv, nullptr, 2048, 1024, 1024, 0);
  gemm_m(xwab, wswab, out2, nullptr, 2048, 96, 1024, 64);    // tanh cols<64
  fuse2_kernel<<<2048, 256, 0, stream>>>(kraw, out1, out2,
                                         tdw2b, tkw2b, taw2b, maw2b, mkw2b,
                                         tdec, taa5, tmia, tmik,
                                         ew, kfin, kkn, bbo);
  scan_kernel<<<32, 256, 0, stream>>>(rr, ew, kfin, vv, kkn, bbo, y);
  gnout_kernel<<<8192, 256, 0, stream>>>(y, rr, kfin, vv, gg, lnw, lnb, faaa, zb);
  gemm_m(zb, woutb, (float*)d_out, nullptr, 2048, 1024, 1024, 0);
}

// Round 13
// 677.291 us; speedup vs baseline: 1.4537x; 1.2229x over previous
//
#include <hip/hip_runtime.h>
#include <hip/hip_bf16.h>

typedef __hip_bfloat16 bf16;

#define B_ 2
#define T_ 1024
#define C_ 1024
#define H_ 16
#define N_ 64

using short8 = __attribute__((ext_vector_type(8))) short;
using f32x4 = __attribute__((ext_vector_type(4))) float;

__device__ __forceinline__ float us2f(unsigned short u) {
  return __uint_as_float(((unsigned int)u) << 16);
}
__device__ __forceinline__ float bs2f(short s) {
  return __uint_as_float(((unsigned int)(unsigned short)s) << 16);
}
__device__ __forceinline__ bf16 f2bf(float f) { return __float2bfloat16(f); }
__device__ __forceinline__ float sigmoidf_(float x) { return 1.0f / (1.0f + expf(-x)); }
__device__ __forceinline__ float softplusf_(float x) {
  return fmaxf(x, 0.0f) + log1pf(expf(-fabsf(x)));
}
// Full 16-lane-row sum, all lanes receive the result. Pure-VALU DPP:
// quad_perm xor1, xor2 give quad sums; row_ror:4 + row_ror:8 complete it.
__device__ __forceinline__ float qsum16(float x) {
  int a = __builtin_amdgcn_update_dpp(0, __float_as_int(x), 0xB1, 0xF, 0xF, true);
  x += __int_as_float(a);                       // quad_perm [1,0,3,2] (xor 1)
  int b = __builtin_amdgcn_update_dpp(0, __float_as_int(x), 0x4E, 0xF, 0xF, true);
  x += __int_as_float(b);                       // quad_perm [2,3,0,1] (xor 2)
  int c = __builtin_amdgcn_update_dpp(0, __float_as_int(x), 0x124, 0xF, 0xF, true);
  x += __int_as_float(c);                       // row_ror:4
  int d = __builtin_amdgcn_update_dpp(0, __float_as_int(x), 0x128, 0xF, 0xF, true);
  x += __int_as_float(d);                       // row_ror:8
  return x;
}

// ---------------- K0: fused weight fp32->bf16 conversion (big weights) ------
__global__ __launch_bounds__(256) void cvt_weights_kernel(
    const float* __restrict__ s0, const float* __restrict__ s1,
    const float* __restrict__ s2, const float* __restrict__ s3,
    const float* __restrict__ s4, const float* __restrict__ s5,
    const float* __restrict__ s6,
    bf16* __restrict__ d0, bf16* __restrict__ d1, bf16* __restrict__ d2,
    bf16* __restrict__ d3, bf16* __restrict__ d4, bf16* __restrict__ d5,
    bf16* __restrict__ d6) {
  long i4 = (long)blockIdx.x * 256 + threadIdx.x;
  const float* s; bf16* d; long off;
  if (i4 < 32768) { s = s0; d = d0; off = i4; }
  else if (i4 < 294912) { s = s1; d = d1; off = i4 - 32768; }
  else if (i4 < 327680) { s = s2; d = d2; off = i4 - 294912; }
  else if (i4 < 360448) { s = s3; d = d3; off = i4 - 327680; }
  else if (i4 < 622592) { s = s4; d = d4; off = i4 - 360448; }
  else if (i4 < 884736) { s = s5; d = d5; off = i4 - 622592; }
  else { s = s6; d = d6; off = i4 - 884736; }
  float4 v = *(const float4*)(s + off * 4);
  d[off * 4 + 0] = f2bf(v.x);
  d[off * 4 + 1] = f2bf(v.y);
  d[off * 4 + 2] = f2bf(v.z);
  d[off * 4 + 3] = f2bf(v.w);
}

// ---------------- K0b: pack small LoRA-1 weights to bf16 --------------------
__global__ __launch_bounds__(256) void cvt_small_kernel(
    const float* __restrict__ tkw1, const float* __restrict__ mkw1,
    const float* __restrict__ tdw1, const float* __restrict__ taw1,
    const float* __restrict__ maw1,
    bf16* __restrict__ wsk, bf16* __restrict__ wswa) {
  long i4 = (long)blockIdx.x * 256 + threadIdx.x;  // < 32768
  const float* s; bf16* d; long so, dof;
  if (i4 < 4096) { s = tkw1; so = i4; d = wsk; dof = i4; }
  else if (i4 < 8192) { s = mkw1; so = i4 - 4096; d = wsk; dof = i4; }
  else if (i4 < 24576) { s = tdw1; so = i4 - 8192; d = wswa; dof = i4 - 8192; }
  else if (i4 < 28672) { s = taw1; so = i4 - 24576; d = wswa; dof = i4 - 8192; }
  else { s = maw1; so = i4 - 28672; d = wswa; dof = i4 - 8192; }
  float4 v = *(const float4*)(s + so * 4);
  d[dof * 4 + 0] = f2bf(v.x);
  d[dof * 4 + 1] = f2bf(v.y);
  d[dof * 4 + 2] = f2bf(v.z);
  d[dof * 4 + 3] = f2bf(v.w);
}

// ---------------- K0c: LoRA-2 weights to bf16 -------------------------------
__global__ __launch_bounds__(256) void cvt_small2_kernel(
    const float* __restrict__ tmw2, const float* __restrict__ tdw2,
    const float* __restrict__ tkw2, const float* __restrict__ taw2,
    const float* __restrict__ maw2, const float* __restrict__ mkw2,
    bf16* __restrict__ tmw2b, bf16* __restrict__ tdw2b,
    bf16* __restrict__ tkw2b, bf16* __restrict__ taw2b,
    bf16* __restrict__ maw2b, bf16* __restrict__ mkw2b) {
  long i4 = (long)blockIdx.x * 256 + threadIdx.x;  // < 65536
  const float* s; bf16* d; long off;
  if (i4 < 32768) { s = tmw2; d = tmw2b; off = i4; }
  else if (i4 < 49152) { s = tdw2; d = tdw2b; off = i4 - 32768; }
  else if (i4 < 53248) { s = tkw2; d = tkw2b; off = i4 - 49152; }
  else if (i4 < 57344) { s = taw2; d = taw2b; off = i4 - 53248; }
  else if (i4 < 61440) { s = maw2; d = maw2b; off = i4 - 57344; }
  else { s = mkw2; d = mkw2b; off = i4 - 61440; }
  float4 v = *(const float4*)(s + off * 4);
  d[off * 4 + 0] = f2bf(v.x);
  d[off * 4 + 1] = f2bf(v.y);
  d[off * 4 + 2] = f2bf(v.z);
  d[off * 4 + 3] = f2bf(v.w);
}

// ---------------- K1: token shift (writes xx f32, xxx bf16) -----------------
__global__ __launch_bounds__(256) void shift_kernel(
    const float* __restrict__ x, const float* __restrict__ tmx,
    float* __restrict__ xx, bf16* __restrict__ xxxb) {
  long idx = (long)blockIdx.x * 256 + threadIdx.x;  // < B*T*C
  int c = (int)(idx & (C_ - 1));
  int t = (int)((idx >> 10) & (T_ - 1));
  float xv = x[idx];
  float xp = (t > 0) ? x[idx - C_] : 0.0f;
  float d = xp - xv;
  xx[idx] = d;
  xxxb[idx] = f2bf(xv + d * tmx[c]);
}

// ---------------- MFMA GEMM: C = A(bf16 MxK) * W^T (W bf16 NxK) -------------
__global__ __launch_bounds__(256) void gemm_mfma_kernel(
    const bf16* __restrict__ A, const bf16* __restrict__ W,
    float* __restrict__ Cf, bf16* __restrict__ Cb,
    int M, int N, int K, int actN) {
  __shared__ __align__(16) bf16 As[64][72];  // 144B row stride, 16B aligned
  __shared__ __align__(16) bf16 Ws[64][72];
  int tid = threadIdx.x;
  int m0 = blockIdx.y << 6, n0 = blockIdx.x << 6;
  int srow = tid >> 2, skg = (tid & 3) << 4;   // staging: row, 16 bf16 per thread
  int wv = tid >> 6, lane = tid & 63;
  int fr = lane & 15, fq = lane >> 4;
  f32x4 acc0 = {0.f, 0.f, 0.f, 0.f}, acc1 = acc0, acc2 = acc0, acc3 = acc0;
  bool wok = (n0 + srow) < N;
  const bf16* Ap = A + (long)(m0 + srow) * K + skg;
  const bf16* Wp = W + (long)(n0 + srow) * K + skg;
  short8 zz = {0, 0, 0, 0, 0, 0, 0, 0};
  for (int k0 = 0; k0 < K; k0 += 64) {
    *(short8*)&As[srow][skg] = *(const short8*)(Ap + k0);
    *(short8*)&As[srow][skg + 8] = *(const short8*)(Ap + k0 + 8);
    *(short8*)&Ws[srow][skg] = wok ? *(const short8*)(Wp + k0) : zz;
    *(short8*)&Ws[srow][skg + 8] = wok ? *(const short8*)(Wp + k0 + 8) : zz;
    __syncthreads();
#pragma unroll
    for (int kk = 0; kk < 2; kk++) {
      int ko = (fq << 3) + (kk << 5);
      short8 af = *(const short8*)&As[(wv << 4) + fr][ko];
      short8 b0 = *(const short8*)&Ws[fr][ko];
      short8 b1 = *(const short8*)&Ws[16 + fr][ko];
      short8 b2 = *(const short8*)&Ws[32 + fr][ko];
      short8 b3 = *(const short8*)&Ws[48 + fr][ko];
      acc0 = __builtin_amdgcn_mfma_f32_16x16x32_bf16(af, b0, acc0, 0, 0, 0);
      acc1 = __builtin_amdgcn_mfma_f32_16x16x32_bf16(af, b1, acc1, 0, 0, 0);
      acc2 = __builtin_amdgcn_mfma_f32_16x16x32_bf16(af, b2, acc2, 0, 0, 0);
      acc3 = __builtin_amdgcn_mfma_f32_16x16x32_bf16(af, b3, acc3, 0, 0, 0);
    }
    __syncthreads();
  }
  int orow = m0 + (wv << 4) + (fq << 2);
  int ocol = n0 + fr;
  f32x4 av[4] = {acc0, acc1, acc2, acc3};
#pragma unroll
  for (int nt = 0; nt < 4; nt++) {
    int col = ocol + (nt << 4);
    if (col < N) {
#pragma unroll
      for (int r = 0; r < 4; r++) {
        float vvv = av[nt][r];
        if (col < actN) vvv = tanhf(vvv);
        long oi = (long)(orow + r) * N + col;
        if (Cb) Cb[oi] = f2bf(vvv); else Cf[oi] = vvv;
      }
    }
  }
}

// ---------------- K3: deltas + build xrg/xwa/xk/xv (bf16 out) ---------------
__global__ __launch_bounds__(256) void mix4_kernel(
    const float* __restrict__ x, const float* __restrict__ xx,
    const float* __restrict__ mix, const float* __restrict__ tmaa,
    const bf16* __restrict__ w2b,
    bf16* __restrict__ xrg, bf16* __restrict__ xwa,
    bf16* __restrict__ xk, bf16* __restrict__ xv) {
  int m = blockIdx.x;
  int tid = threadIdx.x;
  __shared__ float mrow[128];
  if (tid < 128) mrow[tid] = mix[(long)m * 128 + tid];
  __syncthreads();
#pragma unroll
  for (int cc = 0; cc < 4; cc++) {
    int c = tid + (cc << 8);
    long off = (long)m * C_ + c;
    float xb = x[off];
    float xxv = xx[off];
    float res[4];
#pragma unroll
    for (int f = 0; f < 4; f++) {
      const short8* wp = (const short8*)(w2b + (((long)f * C_ + c) << 5));
      float dl = 0.f;
#pragma unroll
      for (int d8 = 0; d8 < 4; d8++) {
        short8 u = wp[d8];
        int db = (f << 5) + (d8 << 3);
#pragma unroll
        for (int e = 0; e < 8; e++) dl += mrow[db + e] * bs2f(u[e]);
      }
      res[f] = xb + xxv * (tmaa[f * C_ + c] + dl);
    }
    xrg[off] = f2bf(res[0]); xwa[off] = f2bf(res[1]);
    xk[off] = f2bf(res[2]); xv[off] = f2bf(res[3]);
  }
}

// ---------------- K5: stage-2 small GEMMs + gates + per-head kk norm --------
__global__ __launch_bounds__(256) void fuse2_kernel(
    const float* __restrict__ kraw, const float* __restrict__ out1,
    const float* __restrict__ out2,
    const bf16* __restrict__ dw2, const bf16* __restrict__ kkw2,
    const bf16* __restrict__ aw2, const bf16* __restrict__ maw2,
    const bf16* __restrict__ mkw2,
    const float* __restrict__ tdec, const float* __restrict__ taa,
    const float* __restrict__ tma, const float* __restrict__ tmk,
    float* __restrict__ ew, float* __restrict__ kfin,
    float* __restrict__ kkn, float* __restrict__ bbo) {
  int m = blockIdx.x, tid = threadIdx.x;
  __shared__ float w1r[64], kk1r[16], a1r[16], ma1r[16], mk1r[16];
  if (tid < 64) w1r[tid] = out2[(long)m * 96 + tid];
  else if (tid < 80) kk1r[tid - 64] = out1[(long)m * 32 + (tid - 64)];
  else if (tid < 96) a1r[tid - 80] = out2[(long)m * 96 + 64 + (tid - 80)];
  else if (tid < 112) ma1r[tid - 96] = out2[(long)m * 96 + 80 + (tid - 96)];
  else if (tid < 128) mk1r[tid - 112] = out1[(long)m * 32 + 16 + (tid - 112)];
  __syncthreads();
  float kkp[4], av[4], wv[4], kr[4], mkv[4];
  float sumsq = 0.f;
#pragma unroll
  for (int j = 0; j < 4; j++) {
    int c = (tid << 2) + j;
    long off = (long)m * C_ + c;
    float wd = 0.f;
    const short8* dp = (const short8*)(dw2 + ((long)c << 6));
#pragma unroll
    for (int d8 = 0; d8 < 8; d8++) {
      short8 u = dp[d8];
      int db = d8 << 3;
#pragma unroll
      for (int e = 0; e < 8; e++) wd += w1r[db + e] * bs2f(u[e]);
    }
    float w = -softplusf_(-(tdec[c] + wd)) - 0.5f;
    wv[j] = w;
    float kd = 0.f, ad = 0.f, mad = 0.f, mkd = 0.f;
    const short8* kp = (const short8*)(kkw2 + ((long)c << 4));
    const short8* ap = (const short8*)(aw2 + ((long)c << 4));
    const short8* mp = (const short8*)(maw2 + ((long)c << 4));
    const short8* qp = (const short8*)(mkw2 + ((long)c << 4));
#pragma unroll
    for (int d8 = 0; d8 < 2; d8++) {
      short8 u1 = kp[d8], u2 = ap[d8], u3 = mp[d8], u4 = qp[d8];
      int db = d8 << 3;
#pragma unroll
      for (int e = 0; e < 8; e++) {
        kd += kk1r[db + e] * bs2f(u1[e]);
        ad += a1r[db + e] * bs2f(u2[e]);
        mad += ma1r[db + e] * bs2f(u3[e]);
        mkd += mk1r[db + e] * bs2f(u4[e]);
      }
    }
    float krw = kraw[off];
    float kkpre = krw + kd;
    kkp[j] = kkpre;
    sumsq += kkpre * kkpre;
    float a = sigmoidf_(taa[c] + ad);
    av[j] = a;
    float ma = sigmoidf_(tma[c] + mad);
    float mk = sigmoidf_(tmk[c] + mkd);
    mkv[j] = mk;
    kr[j] = krw * (ma + a * (1.f - ma));
  }
  sumsq += __shfl_xor(sumsq, 1);
  sumsq += __shfl_xor(sumsq, 2);
  sumsq += __shfl_xor(sumsq, 4);
  sumsq += __shfl_xor(sumsq, 8);
  float rn = 1.0f / fmaxf(sqrtf(sumsq), 1e-12f);
#pragma unroll
  for (int j = 0; j < 4; j++) {
    int c = (tid << 2) + j;
    long off = (long)m * C_ + c;
    float kknv = kkp[j] * rn;
    kkn[off] = kknv;
    bbo[off] = -kknv * av[j];
    ew[off] = expf(wv[j]);
    kfin[off] = kr[j] * expf(wv[j] * mkv[j]);
  }
}

// ---------------- K6: RWKV-7 scan, 128 blocks x 256 threads -----------------
// block = (b,h,rowgroup of 16 rows): rows are independent in the recurrence,
// so the 64x64 state spreads over 4 CUs per (b,h) (round 12 showed one CU is
// VALU-work-bound at 64 rows). Lane = g*16+q: row = rg*16 + wave*4 + g,
// keys 4q..4q+3 -> S[4]/lane. Reductions over the 16 q-lanes via qsum16
// (pure-VALU DPP). Cooperative reg->LDS staging as rounds 10-12.
#define SCHUNK 16
__global__ __launch_bounds__(256) void scan_kernel(
    const float* __restrict__ rB, const float* __restrict__ ewB,
    const float* __restrict__ kB, const float* __restrict__ vB,
    const float* __restrict__ kkB, const float* __restrict__ bbB,
    float* __restrict__ yB) {
  __shared__ __align__(16) float lds[6][SCHUNK * 64];
  int bid = blockIdx.x;          // 0..127
  int bh = bid >> 2, rg = bid & 3;
  int b = bh >> 4, h = bh & 15;
  int tid = threadIdx.x;
  int wave = tid >> 6, lane = tid & 63;
  int g = lane >> 4, q = lane & 15;
  int row = (rg << 4) + (wave << 2) + g;   // this lane's single row
  int kq = q << 2;                         // 4 keys: kq..kq+3
  const long base = ((long)b * T_) * C_ + (h << 6);
  const float* s0 = kkB + base;
  const float* s1 = ewB + base;
  const float* s2 = kB + base;
  const float* s3 = bbB + base;
  const float* s4 = rB + base;
  const float* s5 = vB + base;
  int stok = tid >> 4;           // staging token within chunk (0..15)
  int spc = (tid & 15) << 2;     // float offset within token row
  int lo = (stok << 6) + spc;    // LDS float offset
  float4 rb0, rb1, rb2, rb3, rb4, rb5;
  auto loadc = [&](int c) {
    long go = (long)((c << 4) + stok) * C_ + spc;
    rb0 = *(const float4*)(s0 + go);
    rb1 = *(const float4*)(s1 + go);
    rb2 = *(const float4*)(s2 + go);
    rb3 = *(const float4*)(s3 + go);
    rb4 = *(const float4*)(s4 + go);
    rb5 = *(const float4*)(s5 + go);
  };
  float S0 = 0.f, S1 = 0.f, S2 = 0.f, S3 = 0.f;
  loadc(0);
  for (int c = 0; c < T_ / SCHUNK; c++) {
    __syncthreads();
    *(float4*)&lds[0][lo] = rb0;
    *(float4*)&lds[1][lo] = rb1;
    *(float4*)&lds[2][lo] = rb2;
    *(float4*)&lds[3][lo] = rb3;
    *(float4*)&lds[4][lo] = rb4;
    *(float4*)&lds[5][lo] = rb5;
    __syncthreads();
    if (c + 1 < T_ / SCHUNK) loadc(c + 1);
#pragma unroll 8
    for (int tt = 0; tt < SCHUNK; tt++) {
      int tb = tt << 6;
      float4 kk = *(const float4*)&lds[0][tb + kq];
      float p = S0 * kk.x + S1 * kk.y + S2 * kk.z + S3 * kk.w;
      float sab = qsum16(p);
      float4 ew = *(const float4*)&lds[1][tb + kq];
      float4 bb = *(const float4*)&lds[3][tb + kq];
      float4 k4 = *(const float4*)&lds[2][tb + kq];
      float vv = lds[5][tb + row];
      S0 = S0 * ew.x + sab * bb.x + vv * k4.x;
      S1 = S1 * ew.y + sab * bb.y + vv * k4.y;
      S2 = S2 * ew.z + sab * bb.z + vv * k4.z;
      S3 = S3 * ew.w + sab * bb.w + vv * k4.w;
      float4 r4 = *(const float4*)&lds[4][tb + kq];
      float yp = S0 * r4.x + S1 * r4.y + S2 * r4.z + S3 * r4.w;
      float y = qsum16(yp);
      if (q == 0) yB[base + (long)((c << 4) + tt) * C_ + row] = y;
    }
  }
}

// ---------------- K7: GroupNorm + bonus + gate (bf16 out) -------------------
__global__ __launch_bounds__(256) void gnout_kernel(
    const float* __restrict__ y, const float* __restrict__ r,
    const float* __restrict__ kf, const float* __restrict__ v,
    const float* __restrict__ g,
    const float* __restrict__ lnw, const float* __restrict__ lnb,
    const float* __restrict__ fa, bf16* __restrict__ z) {
  int tid = threadIdx.x;
  int w = tid >> 6, lane = tid & 63;
  int gi = (blockIdx.x << 2) + w;  // (b*T+t)*H + h
  int h = gi & 15, mt = gi >> 4;
  long off = (long)mt * C_ + (h << 6) + lane;
  float yv = y[off];
  float s = yv;
  s += __shfl_xor(s, 1); s += __shfl_xor(s, 2); s += __shfl_xor(s, 4);
  s += __shfl_xor(s, 8); s += __shfl_xor(s, 16); s += __shfl_xor(s, 32);
  float mu = s * (1.0f / 64.0f);
  float d = yv - mu;
  float s2 = d * d;
  s2 += __shfl_xor(s2, 1); s2 += __shfl_xor(s2, 2); s2 += __shfl_xor(s2, 4);
  s2 += __shfl_xor(s2, 8); s2 += __shfl_xor(s2, 16); s2 += __shfl_xor(s2, 32);
  float var = s2 * (1.0f / 64.0f);
  int hc = (h << 6) + lane;
  float dot = r[off] * kf[off] * fa[hc];
  dot += __shfl_xor(dot, 1); dot += __shfl_xor(dot, 2); dot += __shfl_xor(dot, 4);
  dot += __shfl_xor(dot, 8); dot += __shfl_xor(dot, 16); dot += __shfl_xor(dot, 32);
  float yn = d * rsqrtf(var + 0.00064f) * lnw[hc] + lnb[hc];
  z[off] = f2bf((yn + dot * v[off]) * g[off]);
}

extern "C" void kernel_launch(void* const* d_in, const int* in_sizes, int n_in,
                              void* d_out, int out_size, void* d_ws, size_t ws_size,
                              hipStream_t stream) {
  const float* x = (const float*)d_in[0];
  const float* tmx = (const float*)d_in[1];
  const float* tmaa = (const float*)d_in[2];
  const float* tmw1 = (const float*)d_in[3];
  const float* tmw2 = (const float*)d_in[4];
  const float* tdec = (const float*)d_in[5];
  const float* tdw1 = (const float*)d_in[6];
  const float* tdw2 = (const float*)d_in[7];
  const float* taa5 = (const float*)d_in[8];
  const float* taw1 = (const float*)d_in[9];
  const float* taw2 = (const float*)d_in[10];
  const float* tkw1 = (const float*)d_in[11];
  const float* tkw2 = (const float*)d_in[12];
  const float* gw1 = (const float*)d_in[13];
  const float* gw2 = (const float*)d_in[14];
  const float* tmia = (const float*)d_in[15];
  const float* maw1 = (const float*)d_in[16];
  const float* maw2 = (const float*)d_in[17];
  const float* tmik = (const float*)d_in[18];
  const float* mkw1 = (const float*)d_in[19];
  const float* mkw2 = (const float*)d_in[20];
  const float* wrec = (const float*)d_in[21];
  const float* wkey = (const float*)d_in[22];
  const float* wval = (const float*)d_in[23];
  const float* wout = (const float*)d_in[24];
  const float* lnw = (const float*)d_in[25];
  const float* lnb = (const float*)d_in[26];
  const float* faaa = (const float*)d_in[27];

  const long MT = 2048, CC = 1024;
  char* base = (char*)d_ws;
  float* xx = (float*)base;    base += MT * CC * 4;   // also y
  bf16* xxxb = (bf16*)base;    base += MT * CC * 2;
  bf16* xrgb = (bf16*)base;    base += MT * CC * 2;   // ┐ kfin overlays (8MB)
  bf16* xwab = (bf16*)base;    base += MT * CC * 2;   // ┘
  bf16* xkb = (bf16*)base;     base += MT * CC * 2;   // ┐ kkn overlays (8MB)
  bf16* xvb = (bf16*)base;     base += MT * CC * 2;   // ┘
  float* rr = (float*)base;    base += MT * CC * 4;
  float* kraw = (float*)base;  base += MT * CC * 4;   // also ew
  float* vv = (float*)base;    base += MT * CC * 4;
  float* gg = (float*)base;    base += MT * CC * 4;
  float* bbo = (float*)base;   base += MT * CC * 4;
  float* mix = (float*)base;   base += MT * 128 * 4;
  bf16* g1b = (bf16*)base;     base += MT * 128 * 2;
  float* out1 = (float*)base;  base += MT * 32 * 4;   // [kk1|mk1]
  float* out2 = (float*)base;  base += MT * 96 * 4;   // [w1|a1|ma1]
  bf16* zb = (bf16*)base;      base += MT * CC * 2;
  bf16* tmw1b = (bf16*)base;   base += 128 * CC * 2;
  bf16* wrecb = (bf16*)base;   base += CC * CC * 2;
  bf16* gw1b = (bf16*)base;    base += 128 * CC * 2;
  bf16* gw2b = (bf16*)base;    base += CC * 128 * 2;
  bf16* wkeyb = (bf16*)base;   base += CC * CC * 2;
  bf16* wvalb = (bf16*)base;   base += CC * CC * 2;
  bf16* woutb = (bf16*)base;   base += CC * CC * 2;
  bf16* wskb = (bf16*)base;    base += 32 * CC * 2;
  bf16* wswab = (bf16*)base;   base += 96 * CC * 2;
  bf16* tmw2b = (bf16*)base;   base += 4 * CC * 32 * 2;
  bf16* tdw2b = (bf16*)base;   base += CC * 64 * 2;
  bf16* tkw2b = (bf16*)base;   base += CC * 16 * 2;
  bf16* taw2b = (bf16*)base;   base += CC * 16 * 2;
  bf16* maw2b = (bf16*)base;   base += CC * 16 * 2;
  bf16* mkw2b = (bf16*)base;   base += CC * 16 * 2;
  // aliases (dead-buffer reuse, verified non-overlapping in time):
  float* ew = kraw;            // fuse2 reads kraw then writes ew at same offs
  float* kfin = (float*)xrgb;  // xrg/xwa bf16 dead before fuse2
  float* kkn = (float*)xkb;    // xk/xv bf16 dead before fuse2
  float* y = xx;               // xx dead after mix4

  auto gemm_m = [&](const bf16* A, const bf16* W, float* Cf, bf16* Cb,
                    int M, int N, int K, int actN) {
    dim3 grid((N + 63) / 64, M / 64);
    gemm_mfma_kernel<<<grid, 256, 0, stream>>>(A, W, Cf, Cb, M, N, K, actN);
  };

  cvt_weights_kernel<<<4480, 256, 0, stream>>>(
      tmw1, wrec, gw1, gw2, wkey, wval, wout,
      tmw1b, wrecb, gw1b, gw2b, wkeyb, wvalb, woutb);
  cvt_small_kernel<<<128, 256, 0, stream>>>(tkw1, mkw1, tdw1, taw1, maw1,
                                            wskb, wswab);
  cvt_small2_kernel<<<256, 256, 0, stream>>>(tmw2, tdw2, tkw2, taw2, maw2, mkw2,
                                             tmw2b, tdw2b, tkw2b, taw2b,
                                             maw2b, mkw2b);
  shift_kernel<<<8192, 256, 0, stream>>>(x, tmx, xx, xxxb);
  gemm_m(xxxb, tmw1b, mix, nullptr, 2048, 128, 1024, 128);   // tanh all
  mix4_kernel<<<2048, 256, 0, stream>>>(x, xx, mix, tmaa, tmw2b,
                                        xrgb, xwab, xkb, xvb);
  gemm_m(xrgb, wrecb, rr, nullptr, 2048, 1024, 1024, 0);
  gemm_m(xrgb, gw1b, nullptr, g1b, 2048, 128, 1024, 128);    // tanh all
  gemm_m(g1b, gw2b, gg, nullptr, 2048, 1024, 128, 0);
  gemm_m(xkb, wkeyb, kraw, nullptr, 2048, 1024, 1024, 0);
  gemm_m(xkb, wskb, out1, nullptr, 2048, 32, 1024, 16);      // tanh cols<16
  gemm_m(xvb, wvalb, vv, nullptr, 2048, 1024, 1024, 0);
  gemm_m(xwab, wswab, out2, nullptr, 2048, 96, 1024, 64);    // tanh cols<64
  fuse2_kernel<<<2048, 256, 0, stream>>>(kraw, out1, out2,
                                         tdw2b, tkw2b, taw2b, maw2b, mkw2b,
                                         tdec, taa5, tmia, tmik,
                                         ew, kfin, kkn, bbo);
  scan_kernel<<<128, 256, 0, stream>>>(rr, ew, kfin, vv, kkn, bbo, y);
  gnout_kernel<<<8192, 256, 0, stream>>>(y, rr, kfin, vv, gg, lnw, lnb, faaa, zb);
  gemm_m(zb, woutb, (float*)d_out, nullptr, 2048, 1024, 1024, 0);
}